// Round 4
// baseline (244.789 us; speedup 1.0000x reference)
//
#include <hip/hip_runtime.h>
#include <hip/hip_bf16.h>

#define D_ 128
#define T_ 24
#define NPB 24576  /* rows per batch b in expert phase: T*H*W */
#define TSTR 132   /* LDS row stride (floats) for tail stages */

typedef __attribute__((ext_vector_type(8))) short bf16x8;
typedef __attribute__((ext_vector_type(4))) float f32x4;
typedef unsigned short ushortt;

static __device__ __forceinline__ void load8(const float* p, float* dst){
  float4 a = *(const float4*)p; float4 b = *(const float4*)(p+4);
  dst[0]=a.x;dst[1]=a.y;dst[2]=a.z;dst[3]=a.w;dst[4]=b.x;dst[5]=b.y;dst[6]=b.z;dst[7]=b.w;
}
static __device__ __forceinline__ bf16x8 cvt8(const float* f){
  union { bf16x8 v; __hip_bfloat162 h[4]; } u;
#pragma unroll
  for (int i=0;i<4;i++) u.h[i] = __float22bfloat162_rn(make_float2(f[2*i], f[2*i+1]));
  return u.v;
}
static __device__ __forceinline__ void split8(const float* f, bf16x8* hh, bf16x8* ll){
  union { bf16x8 v; __hip_bfloat162 h[4]; } uh, ul;
  float lo[8];
#pragma unroll
  for (int i=0;i<4;i++){
    __hip_bfloat162 p = __float22bfloat162_rn(make_float2(f[2*i], f[2*i+1]));
    uh.h[i] = p;
    lo[2*i]   = f[2*i]   - __bfloat162float(p.x);
    lo[2*i+1] = f[2*i+1] - __bfloat162float(p.y);
  }
#pragma unroll
  for (int i=0;i<4;i++) ul.h[i] = __float22bfloat162_rn(make_float2(lo[2*i], lo[2*i+1]));
  *hh = uh.v; *ll = ul.v;
}

// =====================================================================
// prep: pack weights into MFMA-fragment-linear layout (verified R4).
// =====================================================================
__global__ void prep_frags(const float* __restrict__ cw, const float* __restrict__ ew,
                           ushortt* __restrict__ wfC, ushortt* __restrict__ wfE, int do_e)
{
  const int idx = blockIdx.x*256 + threadIdx.x;
  if (idx < 10240){
    const int l  = idx >> 11;
    const int n  = (idx >> 4) & 127;
    const int k8 = (idx & 15) * 8;
    const float* src = cw + (size_t)((l*128 + n)*128 + k8)*4;   // float4 = 4 taps
    float4 v[8];
#pragma unroll
    for (int kk=0;kk<8;++kk) v[kk] = *(const float4*)&src[kk*4];
    const int fk = k8>>5, q = (k8>>3)&3, ng = n>>4;
    const int lanoff = (q*16 + (n&15))*8;
#pragma unroll
    for (int tap=0; tap<4; ++tap){
      float f[8];
#pragma unroll
      for (int kk=0;kk<8;++kk) f[kk] = ((const float*)&v[kk])[tap];
      bf16x8 hh, ll; split8(f, &hh, &ll);
      *(bf16x8*)&wfC[(size_t)((((l*4+tap)*2+0)*4+fk)*8+ng)*512 + lanoff] = hh;
      *(bf16x8*)&wfC[(size_t)((((l*4+tap)*2+1)*4+fk)*8+ng)*512 + lanoff] = ll;
    }
  } else if (do_e && idx < 10240 + 14336){
    const int j  = idx - 10240;
    const int e  = j >> 11;
    const int n  = (j >> 4) & 127;
    const int k8 = (j & 15) * 8;
    float f[8];
#pragma unroll
    for (int kk=0;kk<8;++kk) f[kk] = ew[(size_t)(e*128 + k8+kk)*128 + n];
    const int fk = k8>>5, q = (k8>>3)&3, ng = n>>4;
    *(bf16x8*)&wfE[(size_t)((e*4+fk)*8+ng)*512 + (q*16 + (n&15))*8] = cvt8(f);
  }
}

// =====================================================================
// conv layer (global->global), MG*16 rows x 128 cols per block.
// Used for L0 (and the fallback chain).
// =====================================================================
template<int MG>
__global__ __launch_bounds__(256, 4)
void conv3(const float* __restrict__ in, float* __restrict__ out,
           const ushortt* __restrict__ wf,
           const float* __restrict__ cb,  const float* __restrict__ gam,
           const float* __restrict__ bet, const float* __restrict__ mn,
           const float* __restrict__ vr,  int n_pix, int lw)
{
  (void)n_pix;
  const int t = threadIdx.x;
  const int w = t>>6, lane = t&63, quad = lane>>4, l16 = lane&15;
  const int nh = w*32;
  const int row0 = blockIdx.x*(MG*16);
  const int Win = 2<<lw;
  int inb[MG];
#pragma unroll
  for (int mg=0; mg<MG; ++mg){
    const int p = row0 + mg*16 + l16;
    const int n   = p >> (2*lw);
    const int rem = p - (n << (2*lw));
    const int oy  = rem >> lw, ox = rem - (oy<<lw);
    inb[mg] = ((n*Win /*Hin==Win*/ + 2*oy)*Win + 2*ox) << 7;
  }
  f32x4 acc[MG][2];
#pragma unroll
  for (int mg=0;mg<MG;++mg){ acc[mg][0]=(f32x4){0,0,0,0}; acc[mg][1]=acc[mg][0]; }

#pragma unroll
  for (int tap=0; tap<4; ++tap){
    const int toff = (((tap>>1)*Win) + (tap&1)) << 7;
#pragma unroll
    for (int fk=0; fk<4; ++fk){
      bf16x8 ah[MG], al[MG];
#pragma unroll
      for (int mg=0; mg<MG; ++mg){
        float f[8]; load8(in + inb[mg] + toff + fk*32 + quad*8, f);
        split8(f, &ah[mg], &al[mg]);
      }
#pragma unroll
      for (int ngl=0; ngl<2; ++ngl){
        const int ng = w*2 + ngl;
        const bf16x8 bh = *(const bf16x8*)&wf[(size_t)(((tap*2+0)*4+fk)*8+ng)*512 + lane*8];
        const bf16x8 bl = *(const bf16x8*)&wf[(size_t)(((tap*2+1)*4+fk)*8+ng)*512 + lane*8];
#pragma unroll
        for (int mg=0; mg<MG; ++mg){
          acc[mg][ngl] = __builtin_amdgcn_mfma_f32_16x16x32_bf16(ah[mg], bh, acc[mg][ngl], 0,0,0);
          acc[mg][ngl] = __builtin_amdgcn_mfma_f32_16x16x32_bf16(ah[mg], bl, acc[mg][ngl], 0,0,0);
          acc[mg][ngl] = __builtin_amdgcn_mfma_f32_16x16x32_bf16(al[mg], bh, acc[mg][ngl], 0,0,0);
        }
      }
    }
  }
#pragma unroll
  for (int ngl=0; ngl<2; ++ngl){
    const int col = nh + ngl*16 + l16;
    const float sc  = gam[col]*rsqrtf(vr[col]+1e-5f);
    const float cbv = cb[col], bt = bet[col], mv = mn[col];
#pragma unroll
    for (int mg=0; mg<MG; ++mg)
#pragma unroll
      for (int r=0; r<4; ++r){
        const int pix = row0 + mg*16 + quad*4 + r;
        float v = acc[mg][ngl][r] + cbv;
        v = sc*(v - mv) + bt;
        out[(size_t)pix*D_ + col] = v>0.f ? v : 0.2f*v;
      }
  }
}

// =====================================================================
// tail stage: 16-row x 128-col conv step reading/writing LDS.
// =====================================================================
template<int WOUT>
static __device__ __forceinline__ void stage_lds(const float* __restrict__ sIn,
    float* __restrict__ sOut, float* __restrict__ gOut,
    const ushortt* __restrict__ wf,
    const float* __restrict__ cb, const float* __restrict__ gam,
    const float* __restrict__ bet, const float* __restrict__ mn,
    const float* __restrict__ vr, int t)
{
  const int w = t>>6, lane = t&63, quad = lane>>4, l16 = lane&15;
  const int nh = w*32;
  const int R  = WOUT*WOUT;
  const int Wi = 2*WOUT;
  const int p  = (l16 < R) ? l16 : 0;
  const int oy = (WOUT==4) ? (p>>2) : (WOUT==2 ? (p>>1) : 0);
  const int ox = (WOUT==4) ? (p&3)  : (WOUT==2 ? (p&1)  : 0);
  const int inb = 2*oy*Wi + 2*ox;
  f32x4 acc[2];
  acc[0]=(f32x4){0,0,0,0}; acc[1]=acc[0];
#pragma unroll
  for (int tap=0; tap<4; ++tap){
    const int toff = (tap>>1)*Wi + (tap&1);
#pragma unroll
    for (int fk=0; fk<4; ++fk){
      float f[8]; load8(sIn + (size_t)(inb+toff)*TSTR + fk*32 + quad*8, f);
      bf16x8 ah, al; split8(f, &ah, &al);
#pragma unroll
      for (int ngl=0; ngl<2; ++ngl){
        const int ng = w*2 + ngl;
        const bf16x8 bh = *(const bf16x8*)&wf[(size_t)(((tap*2+0)*4+fk)*8+ng)*512 + lane*8];
        const bf16x8 bl = *(const bf16x8*)&wf[(size_t)(((tap*2+1)*4+fk)*8+ng)*512 + lane*8];
        acc[ngl] = __builtin_amdgcn_mfma_f32_16x16x32_bf16(ah, bh, acc[ngl], 0,0,0);
        acc[ngl] = __builtin_amdgcn_mfma_f32_16x16x32_bf16(ah, bl, acc[ngl], 0,0,0);
        acc[ngl] = __builtin_amdgcn_mfma_f32_16x16x32_bf16(al, bh, acc[ngl], 0,0,0);
      }
    }
  }
#pragma unroll
  for (int ngl=0; ngl<2; ++ngl){
    const int col = nh + ngl*16 + l16;
    const float sc  = gam[col]*rsqrtf(vr[col]+1e-5f);
    const float cbv = cb[col], btv = bet[col], mv = mn[col];
#pragma unroll
    for (int r=0; r<4; ++r){
      const int row = quad*4 + r;
      if (row < R){
        float v = acc[ngl][r] + cbv;
        v = sc*(v - mv) + btv;
        v = v>0.f ? v : 0.2f*v;
        if (WOUT > 1) sOut[(size_t)row*TSTR + col] = v;
        else          gOut[col] = v;        // R==1: only row 0 stores
      }
    }
  }
}

// =====================================================================
// tail: per-(b,t) block fuses L1 -> L2 -> L3 -> L4 in LDS. 96 blocks.
// =====================================================================
__global__ __launch_bounds__(256, 2)
void tail_kernel(const float* __restrict__ bufA, const ushortt* __restrict__ wfC,
                 const float* __restrict__ cb,  const float* __restrict__ gam,
                 const float* __restrict__ bet, const float* __restrict__ mn,
                 const float* __restrict__ vr,  float* __restrict__ zbuf)
{
  __shared__ float sA[64*TSTR];  // L1 out (8x8)
  __shared__ float sB[16*TSTR];  // L2 out (4x4)
  __shared__ float sC[ 4*TSTR];  // L3 out (2x2)
  const int bt = blockIdx.x;
  const int t = threadIdx.x;
  const int w = t>>6, lane = t&63, quad = lane>>4, l16 = lane&15;
  const int nh = w*32;

  // ---- L1: bufA rows [bt*256, bt*256+256) -> sA (64 rows), MG=4/wave ----
  {
    const ushortt* wf = wfC + 131072;
    int inb[4];
#pragma unroll
    for (int mg=0; mg<4; ++mg){
      const int p = mg*16 + l16;          // local pixel in 8x8
      const int oy = p>>3, ox = p&7;
      inb[mg] = ((bt*16 + 2*oy)*16 + 2*ox) << 7;
    }
    f32x4 acc[4][2];
#pragma unroll
    for (int mg=0;mg<4;++mg){ acc[mg][0]=(f32x4){0,0,0,0}; acc[mg][1]=acc[mg][0]; }
#pragma unroll
    for (int tap=0; tap<4; ++tap){
      const int toff = (((tap>>1)*16) + (tap&1)) << 7;
#pragma unroll
      for (int fk=0; fk<4; ++fk){
        bf16x8 ah[4], al[4];
#pragma unroll
        for (int mg=0; mg<4; ++mg){
          float f[8]; load8(bufA + (size_t)inb[mg] + toff + fk*32 + quad*8, f);
          split8(f, &ah[mg], &al[mg]);
        }
#pragma unroll
        for (int ngl=0; ngl<2; ++ngl){
          const int ng = w*2 + ngl;
          const bf16x8 bh = *(const bf16x8*)&wf[(size_t)(((tap*2+0)*4+fk)*8+ng)*512 + lane*8];
          const bf16x8 bl = *(const bf16x8*)&wf[(size_t)(((tap*2+1)*4+fk)*8+ng)*512 + lane*8];
#pragma unroll
          for (int mg=0; mg<4; ++mg){
            acc[mg][ngl] = __builtin_amdgcn_mfma_f32_16x16x32_bf16(ah[mg], bh, acc[mg][ngl], 0,0,0);
            acc[mg][ngl] = __builtin_amdgcn_mfma_f32_16x16x32_bf16(ah[mg], bl, acc[mg][ngl], 0,0,0);
            acc[mg][ngl] = __builtin_amdgcn_mfma_f32_16x16x32_bf16(al[mg], bh, acc[mg][ngl], 0,0,0);
          }
        }
      }
    }
#pragma unroll
    for (int ngl=0; ngl<2; ++ngl){
      const int col = nh + ngl*16 + l16;
      const float sc  = gam[128+col]*rsqrtf(vr[128+col]+1e-5f);
      const float cbv = cb[128+col], btv = bet[128+col], mv = mn[128+col];
#pragma unroll
      for (int mg=0; mg<4; ++mg)
#pragma unroll
        for (int r=0; r<4; ++r){
          const int row = mg*16 + quad*4 + r;
          float v = acc[mg][ngl][r] + cbv;
          v = sc*(v - mv) + btv;
          sA[(size_t)row*TSTR + col] = v>0.f ? v : 0.2f*v;
        }
    }
  }
  __syncthreads();
  stage_lds<4>(sA, sB, nullptr, wfC + 262144, cb+256, gam+256, bet+256, mn+256, vr+256, t);
  __syncthreads();
  stage_lds<2>(sB, sC, nullptr, wfC + 393216, cb+384, gam+384, bet+384, mn+384, vr+384, t);
  __syncthreads();
  stage_lds<1>(sC, nullptr, zbuf + (size_t)bt*D_, wfC + 524288, cb+512, gam+512, bet+512, mn+512, vr+512, t);
}

// ---- gate: fuse dot + rFFT(1..12) + logits + top-2 softmax (1 block) ----
__global__ void gate_kernel(const float* __restrict__ z, const float* __restrict__ fw,
                            const float* __restrict__ fb, const float* __restrict__ wg,
                            float* __restrict__ gbuf)
{
  __shared__ float s[96];
  __shared__ float amp[4][12];
  __shared__ float logits[4][7];
  const int t = threadIdx.x;
  if (t < 96){
    float a = 0.f;
    for (int d=0; d<D_; d++) a = fmaf(z[t*D_+d], fw[d], a);
    s[t] = a + fb[0];
  }
  __syncthreads();
  if (t < 48){
    const int b = t / 12, kf = (t % 12) + 1;
    float re=0.f, im=0.f;
    for (int tt=0; tt<T_; tt++){
      int ph = (kf*tt) % T_;
      float ang = (float)ph * (6.283185307179586f / (float)T_);
      re = fmaf(s[b*T_+tt], cosf(ang), re);
      im = fmaf(s[b*T_+tt], sinf(ang), im);
    }
    amp[b][t%12] = sqrtf(re*re + im*im) * 0.20412414523193150f;
  }
  __syncthreads();
  if (t < 28){
    const int b = t/7, e = t - (t/7)*7;
    float a = 0.f;
    for (int k=0;k<12;k++) a = fmaf(amp[b][k], wg[k*7+e], a);
    logits[b][e] = a;
  }
  __syncthreads();
  if (t < 4){
    const int b = t;
    int i0=0; float v0=logits[b][0];
    for (int e=1;e<7;e++){ float v=logits[b][e]; if (v > v0){ v0=v; i0=e; } }
    int i1=-1; float v1=-3.4e38f;
    for (int e=0;e<7;e++){ if (e==i0) continue; float v=logits[b][e]; if (v > v1){ v1=v; i1=e; } }
    float ed = expf(v1 - v0);
    gbuf[b*4+0] = 1.f/(1.f+ed);
    gbuf[b*4+1] = ed/(1.f+ed);
    ((int*)gbuf)[b*4+2] = i0;
    ((int*)gbuf)[b*4+3] = i1;
  }
}

// =====================================================================
// expert_lse: pure expert tile, log-sum-exp epilogue (1 exp + 1 log).
// 768 blocks x 2 tiles (grid-stride), 3 blocks/CU steady.
//   out = log(g0 e^u + g1 e^v) = m + log(1 + e^{-|u'-v'|}),
//   u' = u + ln g0, v' = v + ln g1, m = max(u',v').
// c==0 clamp unreachable: 1+e^{-|d|} in (1,2], acc values O(+-10).
// =====================================================================
__global__ __launch_bounds__(256, 4)
void expert_lse(const float* __restrict__ x, const ushortt* __restrict__ wfe,
                const float* __restrict__ eb, const float* __restrict__ gbuf,
                float* __restrict__ outp)
{
  const int t = threadIdx.x;
  const int w = t>>6, lane = t&63, quad = lane>>4, l16 = lane&15;
  const int nh = w*32;

#pragma unroll
  for (int tile=0; tile<2; ++tile){
    const size_t row0 = (size_t)(blockIdx.x + tile*768) * 64;
    const int b = (int)(row0 / NPB);
    const float g0 = gbuf[b*4+0], g1 = gbuf[b*4+1];
    const int e0 = ((const int*)gbuf)[b*4+2];
    const int e1 = ((const int*)gbuf)[b*4+3];
    const float lg0 = __logf(g0), lg1 = __logf(g1);

    f32x4 acc[2][4][2];
#pragma unroll
    for (int e=0;e<2;++e)
#pragma unroll
      for (int mg=0;mg<4;++mg){ acc[e][mg][0]=(f32x4){0,0,0,0}; acc[e][mg][1]=acc[e][mg][0]; }

#pragma unroll
    for (int fk=0; fk<4; ++fk){
      bf16x8 a[4];
#pragma unroll
      for (int mg=0; mg<4; ++mg){
        float f[8]; load8(x + (row0 + mg*16 + l16)*D_ + fk*32 + quad*8, f);
        a[mg] = cvt8(f);
      }
#pragma unroll
      for (int e=0; e<2; ++e){
        const int eg = e ? e1 : e0;
#pragma unroll
        for (int ngl=0; ngl<2; ++ngl){
          const int ng = w*2 + ngl;
          const bf16x8 bb = *(const bf16x8*)&wfe[(size_t)((eg*4+fk)*8+ng)*512 + lane*8];
#pragma unroll
          for (int mg=0; mg<4; ++mg)
            acc[e][mg][ngl] = __builtin_amdgcn_mfma_f32_16x16x32_bf16(a[mg], bb, acc[e][mg][ngl], 0,0,0);
        }
      }
    }
#pragma unroll
    for (int ngl=0; ngl<2; ++ngl){
      const int col = nh + ngl*16 + l16;
      const float be0 = eb[e0*D_ + col] + lg0;
      const float be1 = eb[e1*D_ + col] + lg1;
#pragma unroll
      for (int mg=0; mg<4; ++mg)
#pragma unroll
        for (int r=0; r<4; ++r){
          const size_t row = row0 + mg*16 + quad*4 + r;
          const float u = acc[0][mg][ngl][r] + be0;
          const float v = acc[1][mg][ngl][r] + be1;
          const float m = fmaxf(u, v);
          outp[row*D_ + col] = m + __logf(1.f + __expf(-fabsf(u - v)));
        }
    }
  }
}

// =====================================================================
// expert (fallback path): reads gbuf, optional LDS weight staging.
// =====================================================================
template<bool WF>
__global__ __launch_bounds__(256, 3)
void expert3(const float* __restrict__ x, const float* __restrict__ ew,
             const ushortt* __restrict__ wfe, const float* __restrict__ eb,
             const float* __restrict__ gbuf, float* __restrict__ outp)
{
  __shared__ ushortt wlds[WF ? 16 : 32768];
  const int t = threadIdx.x;
  const int w = t>>6, lane = t&63, quad = lane>>4, l16 = lane&15;
  const int nh = w*32;
  const size_t row0 = (size_t)blockIdx.x * 64;
  const int b = (int)(row0 / NPB);
  const float g0 = gbuf[b*4+0], g1 = gbuf[b*4+1];
  const int e0 = ((const int*)gbuf)[b*4+2];
  const int e1 = ((const int*)gbuf)[b*4+3];

  if (!WF){
    const int el = t>>7, r7 = t&127;
    const int n0 = (r7&31)*4, k0 = (r7>>5)*16;
    const int esel = el ? e1 : e0;
#pragma unroll
    for (int h=0; h<2; ++h)
#pragma unroll
      for (int sub=0; sub<2; ++sub){
        const int kb = h*64 + k0 + sub*8;
        float4 v[8];
#pragma unroll
        for (int kk=0;kk<8;++kk)
          v[kk] = *(const float4*)&ew[(size_t)esel*16384 + (size_t)(kb+kk)*D_ + n0];
        const int fk = kb>>5, q = (kb>>3)&3;
#pragma unroll
        for (int n=0;n<4;++n){
          float f[8];
#pragma unroll
          for (int kk=0;kk<8;++kk) f[kk] = ((const float*)&v[kk])[n];
          *(bf16x8*)&wlds[(size_t)(((el*4+fk)*8 + ((n0+n)>>4))*512 + (q*16 + ((n0+n)&15))*8)] = cvt8(f);
        }
      }
    __syncthreads();
  }

  f32x4 acc[2][4][2];
#pragma unroll
  for (int e=0;e<2;++e)
#pragma unroll
    for (int mg=0;mg<4;++mg){ acc[e][mg][0]=(f32x4){0,0,0,0}; acc[e][mg][1]=acc[e][mg][0]; }

#pragma unroll
  for (int fk=0; fk<4; ++fk){
    bf16x8 a[4];
#pragma unroll
    for (int mg=0; mg<4; ++mg){
      float f[8]; load8(x + (row0 + mg*16 + l16)*D_ + fk*32 + quad*8, f);
      a[mg] = cvt8(f);
    }
#pragma unroll
    for (int e=0; e<2; ++e){
      const int eg = e ? e1 : e0;
#pragma unroll
      for (int ngl=0; ngl<2; ++ngl){
        const int ng = w*2 + ngl;
        bf16x8 bb;
        if (WF) bb = *(const bf16x8*)&wfe[(size_t)((eg*4+fk)*8+ng)*512 + lane*8];
        else    bb = *(const bf16x8*)&wlds[(size_t)((e*4+fk)*8+ng)*512 + lane*8];
#pragma unroll
        for (int mg=0; mg<4; ++mg)
          acc[e][mg][ngl] = __builtin_amdgcn_mfma_f32_16x16x32_bf16(a[mg], bb, acc[e][mg][ngl], 0,0,0);
      }
    }
  }
#pragma unroll
  for (int ngl=0; ngl<2; ++ngl){
    const int col = nh + ngl*16 + l16;
    const float be0 = eb[e0*D_ + col];
    const float be1 = eb[e1*D_ + col];
#pragma unroll
    for (int mg=0; mg<4; ++mg)
#pragma unroll
      for (int r=0; r<4; ++r){
        const size_t row = row0 + mg*16 + quad*4 + r;
        float c = g0*__expf(acc[0][mg][ngl][r] + be0) + g1*__expf(acc[1][mg][ngl][r] + be1);
        if (c == 0.f) c = 2.220446049250313e-16f;
        outp[row*D_ + col] = __logf(c);
      }
  }
}

extern "C" void kernel_launch(void* const* d_in, const int* in_sizes, int n_in,
                              void* d_out, int out_size, void* d_ws, size_t ws_size,
                              hipStream_t stream)
{
  const float* x   = (const float*)d_in[0];
  const float* cw  = (const float*)d_in[1];
  const float* cb  = (const float*)d_in[2];
  const float* gam = (const float*)d_in[3];
  const float* bet = (const float*)d_in[4];
  const float* mn  = (const float*)d_in[5];
  const float* vr  = (const float*)d_in[6];
  const float* fw  = (const float*)d_in[7];
  const float* fb  = (const float*)d_in[8];
  const float* wg  = (const float*)d_in[9];
  const float* ew  = (const float*)d_in[10];
  const float* eb  = (const float*)d_in[11];
  float* out = (float*)d_out;

  // Scratch inside d_out (50.3 MB), fully overwritten by expert at the end:
  //   wfC  [0,        1310720)   conv weight frags (hi/lo bf16)
  //   bufA [1310720,  13893632)  L0 output (24576 x 128 fp32)
  char* sb = (char*)d_out;
  ushortt* wfC = (ushortt*)sb;
  float* bufA  = (float*)(sb + 1310720);

  // Workspace: wfE [0,229376) + zbuf [229376,278528) + gbuf [278528,278592).
  // zbuf/gbuf live in ws because expert blocks read them while d_out fills.
  const size_t WFE_BYTES = (size_t)7*4*8*512*2;  // 229376
  const size_t ZB_BYTES  = (size_t)96*D_*sizeof(float);
  const bool primary = ws_size >= WFE_BYTES + ZB_BYTES + 64;
  ushortt* wfE = (ushortt*)d_ws;
  float* zbuf_ws = (float*)((char*)d_ws + WFE_BYTES);
  float* gbuf_ws = (float*)((char*)d_ws + WFE_BYTES + ZB_BYTES);

  if (primary){
    // 5 dispatches: prep -> L0 -> tail(L1..L4) -> gate -> expert
    prep_frags<<<96, 256, 0, stream>>>(cw, ew, wfC, wfE, 1);
    conv3<2><<<768, 256, 0, stream>>>(x, bufA, wfC, cb, gam, bet, mn, vr, 24576, 4);
    tail_kernel<<<96, 256, 0, stream>>>(bufA, wfC, cb, gam, bet, mn, vr, zbuf_ws);
    gate_kernel<<<1, 128, 0, stream>>>(zbuf_ws, fw, fb, wg, gbuf_ws);
    expert_lse<<<768, 256, 0, stream>>>(x, wfE, eb, gbuf_ws, out);
    return;
  }

  // Fallback: verified 9-dispatch chain (221-223 us baseline)
  float* bufB  = (float*)(sb + 13893632);
  float* zbuf  = (float*)(sb + 17039360);
  float* gbuf  = (float*)d_ws;                 // 64 B
  const bool use_wf = ws_size >= (size_t)(64 + WFE_BYTES);
  ushortt* wfE2 = use_wf ? (ushortt*)((char*)d_ws + 64) : wfC;

  prep_frags<<<96, 256, 0, stream>>>(cw, ew, wfC, wfE2, use_wf ? 1 : 0);
  conv3<2><<<768, 256, 0, stream>>>(x,    bufA, wfC,          cb,     gam,     bet,     mn,     vr,     24576, 4);
  conv3<2><<<192, 256, 0, stream>>>(bufA, bufB, wfC + 131072, cb+128, gam+128, bet+128, mn+128, vr+128,  6144, 3);
  conv3<1><<< 96, 256, 0, stream>>>(bufB, bufA, wfC + 262144, cb+256, gam+256, bet+256, mn+256, vr+256,  1536, 2);
  conv3<1><<< 24, 256, 0, stream>>>(bufA, bufB, wfC + 393216, cb+384, gam+384, bet+384, mn+384, vr+384,   384, 1);
  conv3<1><<<  6, 256, 0, stream>>>(bufB, zbuf, wfC + 524288, cb+512, gam+512, bet+512, mn+512, vr+512,    96, 0);
  gate_kernel<<<1, 128, 0, stream>>>(zbuf, fw, fb, wg, gbuf);
  if (use_wf) expert3<true ><<<1536, 256, 0, stream>>>(x, ew, wfE2, eb, gbuf, out);
  else        expert3<false><<<1536, 256, 0, stream>>>(x, ew, wfE2, eb, gbuf, out);
}

// Round 5
// 230.893 us; speedup vs baseline: 1.0602x; 1.0602x over previous
//
#include <hip/hip_runtime.h>
#include <hip/hip_bf16.h>

#define D_ 128
#define T_ 24
#define NPB 24576  /* rows per batch b in expert phase: T*H*W */
#define TSTR 132   /* LDS row stride (floats) for tail stages */

typedef __attribute__((ext_vector_type(8))) short bf16x8;
typedef __attribute__((ext_vector_type(4))) float f32x4;
typedef unsigned short ushortt;

static __device__ __forceinline__ void load8(const float* p, float* dst){
  float4 a = *(const float4*)p; float4 b = *(const float4*)(p+4);
  dst[0]=a.x;dst[1]=a.y;dst[2]=a.z;dst[3]=a.w;dst[4]=b.x;dst[5]=b.y;dst[6]=b.z;dst[7]=b.w;
}
static __device__ __forceinline__ bf16x8 cvt8(const float* f){
  union { bf16x8 v; __hip_bfloat162 h[4]; } u;
#pragma unroll
  for (int i=0;i<4;i++) u.h[i] = __float22bfloat162_rn(make_float2(f[2*i], f[2*i+1]));
  return u.v;
}
static __device__ __forceinline__ void split8(const float* f, bf16x8* hh, bf16x8* ll){
  union { bf16x8 v; __hip_bfloat162 h[4]; } uh, ul;
  float lo[8];
#pragma unroll
  for (int i=0;i<4;i++){
    __hip_bfloat162 p = __float22bfloat162_rn(make_float2(f[2*i], f[2*i+1]));
    uh.h[i] = p;
    lo[2*i]   = f[2*i]   - __bfloat162float(p.x);
    lo[2*i+1] = f[2*i+1] - __bfloat162float(p.y);
  }
#pragma unroll
  for (int i=0;i<4;i++) ul.h[i] = __float22bfloat162_rn(make_float2(lo[2*i], lo[2*i+1]));
  *hh = uh.v; *ll = ul.v;
}

// =====================================================================
// prep: pack weights into MFMA-fragment-linear layout (verified R4).
// =====================================================================
__global__ void prep_frags(const float* __restrict__ cw, const float* __restrict__ ew,
                           ushortt* __restrict__ wfC, ushortt* __restrict__ wfE, int do_e)
{
  const int idx = blockIdx.x*256 + threadIdx.x;
  if (idx < 10240){
    const int l  = idx >> 11;
    const int n  = (idx >> 4) & 127;
    const int k8 = (idx & 15) * 8;
    const float* src = cw + (size_t)((l*128 + n)*128 + k8)*4;   // float4 = 4 taps
    float4 v[8];
#pragma unroll
    for (int kk=0;kk<8;++kk) v[kk] = *(const float4*)&src[kk*4];
    const int fk = k8>>5, q = (k8>>3)&3, ng = n>>4;
    const int lanoff = (q*16 + (n&15))*8;
#pragma unroll
    for (int tap=0; tap<4; ++tap){
      float f[8];
#pragma unroll
      for (int kk=0;kk<8;++kk) f[kk] = ((const float*)&v[kk])[tap];
      bf16x8 hh, ll; split8(f, &hh, &ll);
      *(bf16x8*)&wfC[(size_t)((((l*4+tap)*2+0)*4+fk)*8+ng)*512 + lanoff] = hh;
      *(bf16x8*)&wfC[(size_t)((((l*4+tap)*2+1)*4+fk)*8+ng)*512 + lanoff] = ll;
    }
  } else if (do_e && idx < 10240 + 14336){
    const int j  = idx - 10240;
    const int e  = j >> 11;
    const int n  = (j >> 4) & 127;
    const int k8 = (j & 15) * 8;
    float f[8];
#pragma unroll
    for (int kk=0;kk<8;++kk) f[kk] = ew[(size_t)(e*128 + k8+kk)*128 + n];
    const int fk = k8>>5, q = (k8>>3)&3, ng = n>>4;
    *(bf16x8*)&wfE[(size_t)((e*4+fk)*8+ng)*512 + (q*16 + (n&15))*8] = cvt8(f);
  }
}

// =====================================================================
// conv layer (global->global), MG*16 rows x 128 cols per block.
// XB: also emit the bf16 high-half of every loaded x element into xb
// (row-major [pix][128] bf16) — frag-ready input for the expert phase.
// split8's hh IS cvt8(f), so this costs only the 16B store.
// =====================================================================
template<int MG, bool XB>
__global__ __launch_bounds__(256, 4)
void conv3(const float* __restrict__ in, float* __restrict__ out,
           ushortt* __restrict__ xb,
           const ushortt* __restrict__ wf,
           const float* __restrict__ cb,  const float* __restrict__ gam,
           const float* __restrict__ bet, const float* __restrict__ mn,
           const float* __restrict__ vr,  int n_pix, int lw)
{
  (void)n_pix;
  const int t = threadIdx.x;
  const int w = t>>6, lane = t&63, quad = lane>>4, l16 = lane&15;
  const int nh = w*32;
  const int row0 = blockIdx.x*(MG*16);
  const int Win = 2<<lw;
  int inb[MG];
#pragma unroll
  for (int mg=0; mg<MG; ++mg){
    const int p = row0 + mg*16 + l16;
    const int n   = p >> (2*lw);
    const int rem = p - (n << (2*lw));
    const int oy  = rem >> lw, ox = rem - (oy<<lw);
    inb[mg] = ((n*Win /*Hin==Win*/ + 2*oy)*Win + 2*ox) << 7;
  }
  f32x4 acc[MG][2];
#pragma unroll
  for (int mg=0;mg<MG;++mg){ acc[mg][0]=(f32x4){0,0,0,0}; acc[mg][1]=acc[mg][0]; }

#pragma unroll
  for (int tap=0; tap<4; ++tap){
    const int toff = (((tap>>1)*Win) + (tap&1)) << 7;
#pragma unroll
    for (int fk=0; fk<4; ++fk){
      bf16x8 ah[MG], al[MG];
#pragma unroll
      for (int mg=0; mg<MG; ++mg){
        float f[8]; load8(in + inb[mg] + toff + fk*32 + quad*8, f);
        split8(f, &ah[mg], &al[mg]);
        if (XB){
          const size_t pix = (size_t)(inb[mg] + toff) >> 7;
          *(bf16x8*)&xb[pix*D_ + fk*32 + quad*8] = ah[mg];
        }
      }
#pragma unroll
      for (int ngl=0; ngl<2; ++ngl){
        const int ng = w*2 + ngl;
        const bf16x8 bh = *(const bf16x8*)&wf[(size_t)(((tap*2+0)*4+fk)*8+ng)*512 + lane*8];
        const bf16x8 bl = *(const bf16x8*)&wf[(size_t)(((tap*2+1)*4+fk)*8+ng)*512 + lane*8];
#pragma unroll
        for (int mg=0; mg<MG; ++mg){
          acc[mg][ngl] = __builtin_amdgcn_mfma_f32_16x16x32_bf16(ah[mg], bh, acc[mg][ngl], 0,0,0);
          acc[mg][ngl] = __builtin_amdgcn_mfma_f32_16x16x32_bf16(ah[mg], bl, acc[mg][ngl], 0,0,0);
          acc[mg][ngl] = __builtin_amdgcn_mfma_f32_16x16x32_bf16(al[mg], bh, acc[mg][ngl], 0,0,0);
        }
      }
    }
  }
#pragma unroll
  for (int ngl=0; ngl<2; ++ngl){
    const int col = nh + ngl*16 + l16;
    const float sc  = gam[col]*rsqrtf(vr[col]+1e-5f);
    const float cbv = cb[col], bt = bet[col], mv = mn[col];
#pragma unroll
    for (int mg=0; mg<MG; ++mg)
#pragma unroll
      for (int r=0; r<4; ++r){
        const int pix = row0 + mg*16 + quad*4 + r;
        float v = acc[mg][ngl][r] + cbv;
        v = sc*(v - mv) + bt;
        out[(size_t)pix*D_ + col] = v>0.f ? v : 0.2f*v;
      }
  }
}

// =====================================================================
// tail stage: 16-row x 128-col conv step reading/writing LDS.
// =====================================================================
template<int WOUT>
static __device__ __forceinline__ void stage_lds(const float* __restrict__ sIn,
    float* __restrict__ sOut, float* __restrict__ gOut,
    const ushortt* __restrict__ wf,
    const float* __restrict__ cb, const float* __restrict__ gam,
    const float* __restrict__ bet, const float* __restrict__ mn,
    const float* __restrict__ vr, int t)
{
  const int w = t>>6, lane = t&63, quad = lane>>4, l16 = lane&15;
  const int nh = w*32;
  const int R  = WOUT*WOUT;
  const int Wi = 2*WOUT;
  const int p  = (l16 < R) ? l16 : 0;
  const int oy = (WOUT==4) ? (p>>2) : (WOUT==2 ? (p>>1) : 0);
  const int ox = (WOUT==4) ? (p&3)  : (WOUT==2 ? (p&1)  : 0);
  const int inb = 2*oy*Wi + 2*ox;
  f32x4 acc[2];
  acc[0]=(f32x4){0,0,0,0}; acc[1]=acc[0];
#pragma unroll
  for (int tap=0; tap<4; ++tap){
    const int toff = (tap>>1)*Wi + (tap&1);
#pragma unroll
    for (int fk=0; fk<4; ++fk){
      float f[8]; load8(sIn + (size_t)(inb+toff)*TSTR + fk*32 + quad*8, f);
      bf16x8 ah, al; split8(f, &ah, &al);
#pragma unroll
      for (int ngl=0; ngl<2; ++ngl){
        const int ng = w*2 + ngl;
        const bf16x8 bh = *(const bf16x8*)&wf[(size_t)(((tap*2+0)*4+fk)*8+ng)*512 + lane*8];
        const bf16x8 bl = *(const bf16x8*)&wf[(size_t)(((tap*2+1)*4+fk)*8+ng)*512 + lane*8];
        acc[ngl] = __builtin_amdgcn_mfma_f32_16x16x32_bf16(ah, bh, acc[ngl], 0,0,0);
        acc[ngl] = __builtin_amdgcn_mfma_f32_16x16x32_bf16(ah, bl, acc[ngl], 0,0,0);
        acc[ngl] = __builtin_amdgcn_mfma_f32_16x16x32_bf16(al, bh, acc[ngl], 0,0,0);
      }
    }
  }
#pragma unroll
  for (int ngl=0; ngl<2; ++ngl){
    const int col = nh + ngl*16 + l16;
    const float sc  = gam[col]*rsqrtf(vr[col]+1e-5f);
    const float cbv = cb[col], btv = bet[col], mv = mn[col];
#pragma unroll
    for (int r=0; r<4; ++r){
      const int row = quad*4 + r;
      if (row < R){
        float v = acc[ngl][r] + cbv;
        v = sc*(v - mv) + btv;
        v = v>0.f ? v : 0.2f*v;
        if (WOUT > 1) sOut[(size_t)row*TSTR + col] = v;
        else          gOut[col] = v;        // R==1: only row 0 stores
      }
    }
  }
}

// =====================================================================
// tail: per-(b,t) block fuses L1 -> L2 -> L3 -> L4 in LDS. 96 blocks.
// =====================================================================
__global__ __launch_bounds__(256, 2)
void tail_kernel(const float* __restrict__ bufA, const ushortt* __restrict__ wfC,
                 const float* __restrict__ cb,  const float* __restrict__ gam,
                 const float* __restrict__ bet, const float* __restrict__ mn,
                 const float* __restrict__ vr,  float* __restrict__ zbuf)
{
  __shared__ float sA[64*TSTR];  // L1 out (8x8)
  __shared__ float sB[16*TSTR];  // L2 out (4x4)
  __shared__ float sC[ 4*TSTR];  // L3 out (2x2)
  const int bt = blockIdx.x;
  const int t = threadIdx.x;
  const int w = t>>6, lane = t&63, quad = lane>>4, l16 = lane&15;
  const int nh = w*32;

  // ---- L1: bufA rows [bt*256, bt*256+256) -> sA (64 rows), MG=4/wave ----
  {
    const ushortt* wf = wfC + 131072;
    int inb[4];
#pragma unroll
    for (int mg=0; mg<4; ++mg){
      const int p = mg*16 + l16;          // local pixel in 8x8
      const int oy = p>>3, ox = p&7;
      inb[mg] = ((bt*16 + 2*oy)*16 + 2*ox) << 7;
    }
    f32x4 acc[4][2];
#pragma unroll
    for (int mg=0;mg<4;++mg){ acc[mg][0]=(f32x4){0,0,0,0}; acc[mg][1]=acc[mg][0]; }
#pragma unroll
    for (int tap=0; tap<4; ++tap){
      const int toff = (((tap>>1)*16) + (tap&1)) << 7;
#pragma unroll
      for (int fk=0; fk<4; ++fk){
        bf16x8 ah[4], al[4];
#pragma unroll
        for (int mg=0; mg<4; ++mg){
          float f[8]; load8(bufA + (size_t)inb[mg] + toff + fk*32 + quad*8, f);
          split8(f, &ah[mg], &al[mg]);
        }
#pragma unroll
        for (int ngl=0; ngl<2; ++ngl){
          const int ng = w*2 + ngl;
          const bf16x8 bh = *(const bf16x8*)&wf[(size_t)(((tap*2+0)*4+fk)*8+ng)*512 + lane*8];
          const bf16x8 bl = *(const bf16x8*)&wf[(size_t)(((tap*2+1)*4+fk)*8+ng)*512 + lane*8];
#pragma unroll
          for (int mg=0; mg<4; ++mg){
            acc[mg][ngl] = __builtin_amdgcn_mfma_f32_16x16x32_bf16(ah[mg], bh, acc[mg][ngl], 0,0,0);
            acc[mg][ngl] = __builtin_amdgcn_mfma_f32_16x16x32_bf16(ah[mg], bl, acc[mg][ngl], 0,0,0);
            acc[mg][ngl] = __builtin_amdgcn_mfma_f32_16x16x32_bf16(al[mg], bh, acc[mg][ngl], 0,0,0);
          }
        }
      }
    }
#pragma unroll
    for (int ngl=0; ngl<2; ++ngl){
      const int col = nh + ngl*16 + l16;
      const float sc  = gam[128+col]*rsqrtf(vr[128+col]+1e-5f);
      const float cbv = cb[128+col], btv = bet[128+col], mv = mn[128+col];
#pragma unroll
      for (int mg=0; mg<4; ++mg)
#pragma unroll
        for (int r=0; r<4; ++r){
          const int row = mg*16 + quad*4 + r;
          float v = acc[mg][ngl][r] + cbv;
          v = sc*(v - mv) + btv;
          sA[(size_t)row*TSTR + col] = v>0.f ? v : 0.2f*v;
        }
    }
  }
  __syncthreads();
  stage_lds<4>(sA, sB, nullptr, wfC + 262144, cb+256, gam+256, bet+256, mn+256, vr+256, t);
  __syncthreads();
  stage_lds<2>(sB, sC, nullptr, wfC + 393216, cb+384, gam+384, bet+384, mn+384, vr+384, t);
  __syncthreads();
  stage_lds<1>(sC, nullptr, zbuf + (size_t)bt*D_, wfC + 524288, cb+512, gam+512, bet+512, mn+512, vr+512, t);
}

// ---- gate: fuse dot + rFFT(1..12) + logits + top-2 softmax (1 block) ----
__global__ void gate_kernel(const float* __restrict__ z, const float* __restrict__ fw,
                            const float* __restrict__ fb, const float* __restrict__ wg,
                            float* __restrict__ gbuf)
{
  __shared__ float s[96];
  __shared__ float amp[4][12];
  __shared__ float logits[4][7];
  const int t = threadIdx.x;
  if (t < 96){
    float a = 0.f;
    for (int d=0; d<D_; d++) a = fmaf(z[t*D_+d], fw[d], a);
    s[t] = a + fb[0];
  }
  __syncthreads();
  if (t < 48){
    const int b = t / 12, kf = (t % 12) + 1;
    float re=0.f, im=0.f;
    for (int tt=0; tt<T_; tt++){
      int ph = (kf*tt) % T_;
      float ang = (float)ph * (6.283185307179586f / (float)T_);
      re = fmaf(s[b*T_+tt], cosf(ang), re);
      im = fmaf(s[b*T_+tt], sinf(ang), im);
    }
    amp[b][t%12] = sqrtf(re*re + im*im) * 0.20412414523193150f;
  }
  __syncthreads();
  if (t < 28){
    const int b = t/7, e = t - (t/7)*7;
    float a = 0.f;
    for (int k=0;k<12;k++) a = fmaf(amp[b][k], wg[k*7+e], a);
    logits[b][e] = a;
  }
  __syncthreads();
  if (t < 4){
    const int b = t;
    int i0=0; float v0=logits[b][0];
    for (int e=1;e<7;e++){ float v=logits[b][e]; if (v > v0){ v0=v; i0=e; } }
    int i1=-1; float v1=-3.4e38f;
    for (int e=0;e<7;e++){ if (e==i0) continue; float v=logits[b][e]; if (v > v1){ v1=v; i1=e; } }
    float ed = expf(v1 - v0);
    gbuf[b*4+0] = 1.f/(1.f+ed);
    gbuf[b*4+1] = ed/(1.f+ed);
    ((int*)gbuf)[b*4+2] = i0;
    ((int*)gbuf)[b*4+3] = i1;
  }
}

// =====================================================================
// expert_xb: reads frag-ready bf16 xb (half the bytes of fp32 x, zero
// cvt VALU, 4-VGPR frags). 1536 blocks x 1 tile (64 rows). LSE epilogue:
//   out = log(g0 e^u + g1 e^v) = m + log(1 + e^{-|u'-v'|}).
// =====================================================================
__global__ __launch_bounds__(256, 4)
void expert_xb(const ushortt* __restrict__ xb, const ushortt* __restrict__ wfe,
               const float* __restrict__ eb, const float* __restrict__ gbuf,
               float* __restrict__ outp)
{
  const int t = threadIdx.x;
  const int w = t>>6, lane = t&63, quad = lane>>4, l16 = lane&15;
  const int nh = w*32;
  const size_t row0 = (size_t)blockIdx.x * 64;
  const int b = (int)(row0 / NPB);
  const float g0 = gbuf[b*4+0], g1 = gbuf[b*4+1];
  const int e0 = ((const int*)gbuf)[b*4+2];
  const int e1 = ((const int*)gbuf)[b*4+3];
  const float lg0 = __logf(g0), lg1 = __logf(g1);

  f32x4 acc[2][4][2];
#pragma unroll
  for (int e=0;e<2;++e)
#pragma unroll
    for (int mg=0;mg<4;++mg){ acc[e][mg][0]=(f32x4){0,0,0,0}; acc[e][mg][1]=acc[e][mg][0]; }

#pragma unroll
  for (int fk=0; fk<4; ++fk){
    bf16x8 a[4];
#pragma unroll
    for (int mg=0; mg<4; ++mg)
      a[mg] = *(const bf16x8*)&xb[(row0 + mg*16 + l16)*D_ + fk*32 + quad*8];
#pragma unroll
    for (int e=0; e<2; ++e){
      const int eg = e ? e1 : e0;
#pragma unroll
      for (int ngl=0; ngl<2; ++ngl){
        const int ng = w*2 + ngl;
        const bf16x8 bb = *(const bf16x8*)&wfe[(size_t)((eg*4+fk)*8+ng)*512 + lane*8];
#pragma unroll
        for (int mg=0; mg<4; ++mg)
          acc[e][mg][ngl] = __builtin_amdgcn_mfma_f32_16x16x32_bf16(a[mg], bb, acc[e][mg][ngl], 0,0,0);
      }
    }
  }
#pragma unroll
  for (int ngl=0; ngl<2; ++ngl){
    const int col = nh + ngl*16 + l16;
    const float be0 = eb[e0*D_ + col] + lg0;
    const float be1 = eb[e1*D_ + col] + lg1;
#pragma unroll
    for (int mg=0; mg<4; ++mg)
#pragma unroll
      for (int r=0; r<4; ++r){
        const size_t row = row0 + mg*16 + quad*4 + r;
        const float u = acc[0][mg][ngl][r] + be0;
        const float v = acc[1][mg][ngl][r] + be1;
        const float m = fmaxf(u, v);
        outp[row*D_ + col] = m + __logf(1.f + __expf(-fabsf(u - v)));
      }
  }
}

// =====================================================================
// expert (fallback path): reads fp32 x + gbuf, optional LDS staging.
// =====================================================================
template<bool WF>
__global__ __launch_bounds__(256, 3)
void expert3(const float* __restrict__ x, const float* __restrict__ ew,
             const ushortt* __restrict__ wfe, const float* __restrict__ eb,
             const float* __restrict__ gbuf, float* __restrict__ outp)
{
  __shared__ ushortt wlds[WF ? 16 : 32768];
  const int t = threadIdx.x;
  const int w = t>>6, lane = t&63, quad = lane>>4, l16 = lane&15;
  const int nh = w*32;
  const size_t row0 = (size_t)blockIdx.x * 64;
  const int b = (int)(row0 / NPB);
  const float g0 = gbuf[b*4+0], g1 = gbuf[b*4+1];
  const int e0 = ((const int*)gbuf)[b*4+2];
  const int e1 = ((const int*)gbuf)[b*4+3];

  if (!WF){
    const int el = t>>7, r7 = t&127;
    const int n0 = (r7&31)*4, k0 = (r7>>5)*16;
    const int esel = el ? e1 : e0;
#pragma unroll
    for (int h=0; h<2; ++h)
#pragma unroll
      for (int sub=0; sub<2; ++sub){
        const int kb = h*64 + k0 + sub*8;
        float4 v[8];
#pragma unroll
        for (int kk=0;kk<8;++kk)
          v[kk] = *(const float4*)&ew[(size_t)esel*16384 + (size_t)(kb+kk)*D_ + n0];
        const int fk = kb>>5, q = (kb>>3)&3;
#pragma unroll
        for (int n=0;n<4;++n){
          float f[8];
#pragma unroll
          for (int kk=0;kk<8;++kk) f[kk] = ((const float*)&v[kk])[n];
          *(bf16x8*)&wlds[(size_t)(((el*4+fk)*8 + ((n0+n)>>4))*512 + (q*16 + ((n0+n)&15))*8)] = cvt8(f);
        }
      }
    __syncthreads();
  }

  f32x4 acc[2][4][2];
#pragma unroll
  for (int e=0;e<2;++e)
#pragma unroll
    for (int mg=0;mg<4;++mg){ acc[e][mg][0]=(f32x4){0,0,0,0}; acc[e][mg][1]=acc[e][mg][0]; }

#pragma unroll
  for (int fk=0; fk<4; ++fk){
    bf16x8 a[4];
#pragma unroll
    for (int mg=0; mg<4; ++mg){
      float f[8]; load8(x + (row0 + mg*16 + l16)*D_ + fk*32 + quad*8, f);
      a[mg] = cvt8(f);
    }
#pragma unroll
    for (int e=0; e<2; ++e){
      const int eg = e ? e1 : e0;
#pragma unroll
      for (int ngl=0; ngl<2; ++ngl){
        const int ng = w*2 + ngl;
        bf16x8 bb;
        if (WF) bb = *(const bf16x8*)&wfe[(size_t)((eg*4+fk)*8+ng)*512 + lane*8];
        else    bb = *(const bf16x8*)&wlds[(size_t)((e*4+fk)*8+ng)*512 + lane*8];
#pragma unroll
        for (int mg=0; mg<4; ++mg)
          acc[e][mg][ngl] = __builtin_amdgcn_mfma_f32_16x16x32_bf16(a[mg], bb, acc[e][mg][ngl], 0,0,0);
      }
    }
  }
#pragma unroll
  for (int ngl=0; ngl<2; ++ngl){
    const int col = nh + ngl*16 + l16;
    const float be0 = eb[e0*D_ + col];
    const float be1 = eb[e1*D_ + col];
#pragma unroll
    for (int mg=0; mg<4; ++mg)
#pragma unroll
      for (int r=0; r<4; ++r){
        const size_t row = row0 + mg*16 + quad*4 + r;
        float c = g0*__expf(acc[0][mg][ngl][r] + be0) + g1*__expf(acc[1][mg][ngl][r] + be1);
        if (c == 0.f) c = 2.220446049250313e-16f;
        outp[row*D_ + col] = __logf(c);
      }
  }
}

extern "C" void kernel_launch(void* const* d_in, const int* in_sizes, int n_in,
                              void* d_out, int out_size, void* d_ws, size_t ws_size,
                              hipStream_t stream)
{
  const float* x   = (const float*)d_in[0];
  const float* cw  = (const float*)d_in[1];
  const float* cb  = (const float*)d_in[2];
  const float* gam = (const float*)d_in[3];
  const float* bet = (const float*)d_in[4];
  const float* mn  = (const float*)d_in[5];
  const float* vr  = (const float*)d_in[6];
  const float* fw  = (const float*)d_in[7];
  const float* fb  = (const float*)d_in[8];
  const float* wg  = (const float*)d_in[9];
  const float* ew  = (const float*)d_in[10];
  const float* eb  = (const float*)d_in[11];
  float* out = (float*)d_out;

  // Scratch inside d_out (50.3 MB), fully overwritten by expert at the end:
  //   wfC  [0,        1310720)   conv weight frags (hi/lo bf16)
  //   bufA [1310720,  13893632)  L0 output (24576 x 128 fp32)
  char* sb = (char*)d_out;
  ushortt* wfC = (ushortt*)sb;
  float* bufA  = (float*)(sb + 1310720);

  // Workspace (expert-phase inputs must NOT live in d_out — expert blocks
  // overwrite d_out while others still read):
  //   wfE  [0,      229376)   expert weight frags
  //   zbuf [229376, 278528)   96x128 fp32 (L4 out)
  //   gbuf [278528, 278592)   gates
  //   xb   [278592, 25444416) 98304x128 bf16 frag-ready x copy
  const size_t WFE_BYTES = (size_t)7*4*8*512*2;          // 229376
  const size_t ZB_BYTES  = (size_t)96*D_*sizeof(float);  // 49152
  const size_t XB_OFF    = WFE_BYTES + ZB_BYTES + 64;    // 278592 (16B aligned)
  const size_t XB_BYTES  = (size_t)98304*D_*2;           // 25165824
  const bool primary = ws_size >= XB_OFF + XB_BYTES;
  ushortt* wfE   = (ushortt*)d_ws;
  float* zbuf_ws = (float*)((char*)d_ws + WFE_BYTES);
  float* gbuf_ws = (float*)((char*)d_ws + WFE_BYTES + ZB_BYTES);
  ushortt* xb    = (ushortt*)((char*)d_ws + XB_OFF);

  if (primary){
    // 5 dispatches: prep -> L0(+xb emit) -> tail(L1..L4) -> gate -> expert
    prep_frags<<<96, 256, 0, stream>>>(cw, ew, wfC, wfE, 1);
    conv3<2,true><<<768, 256, 0, stream>>>(x, bufA, xb, wfC, cb, gam, bet, mn, vr, 24576, 4);
    tail_kernel<<<96, 256, 0, stream>>>(bufA, wfC, cb, gam, bet, mn, vr, zbuf_ws);
    gate_kernel<<<1, 128, 0, stream>>>(zbuf_ws, fw, fb, wg, gbuf_ws);
    expert_xb<<<1536, 256, 0, stream>>>(xb, wfE, eb, gbuf_ws, out);
    return;
  }

  // Fallback: verified 9-dispatch chain (221-223 us baseline)
  float* bufB  = (float*)(sb + 13893632);
  float* zbuf  = (float*)(sb + 17039360);
  float* gbuf  = (float*)d_ws;                 // 64 B
  const bool use_wf = ws_size >= (size_t)(64 + WFE_BYTES);
  ushortt* wfE2 = use_wf ? (ushortt*)((char*)d_ws + 64) : wfC;

  prep_frags<<<96, 256, 0, stream>>>(cw, ew, wfC, wfE2, use_wf ? 1 : 0);
  conv3<2,false><<<768, 256, 0, stream>>>(x,    bufA, nullptr, wfC,          cb,     gam,     bet,     mn,     vr,     24576, 4);
  conv3<2,false><<<192, 256, 0, stream>>>(bufA, bufB, nullptr, wfC + 131072, cb+128, gam+128, bet+128, mn+128, vr+128,  6144, 3);
  conv3<1,false><<< 96, 256, 0, stream>>>(bufB, bufA, nullptr, wfC + 262144, cb+256, gam+256, bet+256, mn+256, vr+256,  1536, 2);
  conv3<1,false><<< 24, 256, 0, stream>>>(bufA, bufB, nullptr, wfC + 393216, cb+384, gam+384, bet+384, mn+384, vr+384,   384, 1);
  conv3<1,false><<<  6, 256, 0, stream>>>(bufB, zbuf, nullptr, wfC + 524288, cb+512, gam+512, bet+512, mn+512, vr+512,    96, 0);
  gate_kernel<<<1, 128, 0, stream>>>(zbuf, fw, fb, wg, gbuf);
  if (use_wf) expert3<true ><<<1536, 256, 0, stream>>>(x, ew, wfE2, eb, gbuf, out);
  else        expert3<false><<<1536, 256, 0, stream>>>(x, ew, wfE2, eb, gbuf, out);
}

// Round 6
// 223.908 us; speedup vs baseline: 1.0933x; 1.0312x over previous
//
#include <hip/hip_runtime.h>
#include <hip/hip_bf16.h>

#define D_ 128
#define T_ 24
#define NPB 24576  /* rows per batch b in expert phase: T*H*W */
#define TSTR 132   /* LDS row stride (floats) for tail stages */

typedef __attribute__((ext_vector_type(8))) short bf16x8;
typedef __attribute__((ext_vector_type(4))) float f32x4;
typedef unsigned short ushortt;

static __device__ __forceinline__ void load8(const float* p, float* dst){
  float4 a = *(const float4*)p; float4 b = *(const float4*)(p+4);
  dst[0]=a.x;dst[1]=a.y;dst[2]=a.z;dst[3]=a.w;dst[4]=b.x;dst[5]=b.y;dst[6]=b.z;dst[7]=b.w;
}
static __device__ __forceinline__ bf16x8 cvt8(const float* f){
  union { bf16x8 v; __hip_bfloat162 h[4]; } u;
#pragma unroll
  for (int i=0;i<4;i++) u.h[i] = __float22bfloat162_rn(make_float2(f[2*i], f[2*i+1]));
  return u.v;
}
static __device__ __forceinline__ void split8(const float* f, bf16x8* hh, bf16x8* ll){
  union { bf16x8 v; __hip_bfloat162 h[4]; } uh, ul;
  float lo[8];
#pragma unroll
  for (int i=0;i<4;i++){
    __hip_bfloat162 p = __float22bfloat162_rn(make_float2(f[2*i], f[2*i+1]));
    uh.h[i] = p;
    lo[2*i]   = f[2*i]   - __bfloat162float(p.x);
    lo[2*i+1] = f[2*i+1] - __bfloat162float(p.y);
  }
#pragma unroll
  for (int i=0;i<4;i++) ul.h[i] = __float22bfloat162_rn(make_float2(lo[2*i], lo[2*i+1]));
  *hh = uh.v; *ll = ul.v;
}

// =====================================================================
// prep: pack weights into MFMA-fragment-linear layout (verified R4).
// =====================================================================
__global__ void prep_frags(const float* __restrict__ cw, const float* __restrict__ ew,
                           ushortt* __restrict__ wfC, ushortt* __restrict__ wfE, int do_e)
{
  const int idx = blockIdx.x*256 + threadIdx.x;
  if (idx < 10240){
    const int l  = idx >> 11;
    const int n  = (idx >> 4) & 127;
    const int k8 = (idx & 15) * 8;
    const float* src = cw + (size_t)((l*128 + n)*128 + k8)*4;   // float4 = 4 taps
    float4 v[8];
#pragma unroll
    for (int kk=0;kk<8;++kk) v[kk] = *(const float4*)&src[kk*4];
    const int fk = k8>>5, q = (k8>>3)&3, ng = n>>4;
    const int lanoff = (q*16 + (n&15))*8;
#pragma unroll
    for (int tap=0; tap<4; ++tap){
      float f[8];
#pragma unroll
      for (int kk=0;kk<8;++kk) f[kk] = ((const float*)&v[kk])[tap];
      bf16x8 hh, ll; split8(f, &hh, &ll);
      *(bf16x8*)&wfC[(size_t)((((l*4+tap)*2+0)*4+fk)*8+ng)*512 + lanoff] = hh;
      *(bf16x8*)&wfC[(size_t)((((l*4+tap)*2+1)*4+fk)*8+ng)*512 + lanoff] = ll;
    }
  } else if (do_e && idx < 10240 + 14336){
    const int j  = idx - 10240;
    const int e  = j >> 11;
    const int n  = (j >> 4) & 127;
    const int k8 = (j & 15) * 8;
    float f[8];
#pragma unroll
    for (int kk=0;kk<8;++kk) f[kk] = ew[(size_t)(e*128 + k8+kk)*128 + n];
    const int fk = k8>>5, q = (k8>>3)&3, ng = n>>4;
    *(bf16x8*)&wfE[(size_t)((e*4+fk)*8+ng)*512 + (q*16 + (n&15))*8] = cvt8(f);
  }
}

// =====================================================================
// conv0_xb: L0 specialized (lw=4, Win=32), MG=1 -> 1536 blocks (6/CU,
// 75% occ ceiling vs 37.5% at MG=2). xb emit filtered to fk==wave so
// each bf16 line is stored exactly once (R5 stored 4x).
// =====================================================================
__global__ __launch_bounds__(256, 8)
void conv0_xb(const float* __restrict__ in, float* __restrict__ out,
              ushortt* __restrict__ xb, const ushortt* __restrict__ wf,
              const float* __restrict__ cb,  const float* __restrict__ gam,
              const float* __restrict__ bet, const float* __restrict__ mn,
              const float* __restrict__ vr)
{
  const int t = threadIdx.x;
  const int w = t>>6, lane = t&63, quad = lane>>4, l16 = lane&15;
  const int nh = w*32;
  const int row0 = blockIdx.x*16;
  const int p = row0 + l16;
  const int n   = p >> 8;
  const int rem = p & 255;
  const int oy  = rem >> 4, ox = rem & 15;
  const int inb = ((n*32 + 2*oy)*32 + 2*ox) << 7;

  f32x4 acc[2];
  acc[0]=(f32x4){0,0,0,0}; acc[1]=acc[0];

#pragma unroll
  for (int tap=0; tap<4; ++tap){
    const int toff = (((tap>>1)*32) + (tap&1)) << 7;
#pragma unroll
    for (int fk=0; fk<4; ++fk){
      float f[8]; load8(in + inb + toff + fk*32 + quad*8, f);
      bf16x8 ah, al; split8(f, &ah, &al);
      if (fk == w){   // wave-uniform: each xb line written exactly once
        const size_t pix = (size_t)(inb + toff) >> 7;
        *(bf16x8*)&xb[pix*D_ + fk*32 + quad*8] = ah;
      }
#pragma unroll
      for (int ngl=0; ngl<2; ++ngl){
        const int ng = w*2 + ngl;
        const bf16x8 bh = *(const bf16x8*)&wf[(size_t)(((tap*2+0)*4+fk)*8+ng)*512 + lane*8];
        const bf16x8 bl = *(const bf16x8*)&wf[(size_t)(((tap*2+1)*4+fk)*8+ng)*512 + lane*8];
        acc[ngl] = __builtin_amdgcn_mfma_f32_16x16x32_bf16(ah, bh, acc[ngl], 0,0,0);
        acc[ngl] = __builtin_amdgcn_mfma_f32_16x16x32_bf16(ah, bl, acc[ngl], 0,0,0);
        acc[ngl] = __builtin_amdgcn_mfma_f32_16x16x32_bf16(al, bh, acc[ngl], 0,0,0);
      }
    }
  }
#pragma unroll
  for (int ngl=0; ngl<2; ++ngl){
    const int col = nh + ngl*16 + l16;
    const float sc  = gam[col]*rsqrtf(vr[col]+1e-5f);
    const float cbv = cb[col], bt = bet[col], mv = mn[col];
#pragma unroll
    for (int r=0; r<4; ++r){
      const int pix = row0 + quad*4 + r;
      float v = acc[ngl][r] + cbv;
      v = sc*(v - mv) + bt;
      out[(size_t)pix*D_ + col] = v>0.f ? v : 0.2f*v;
    }
  }
}

// =====================================================================
// conv layer (global->global), MG*16 rows x 128 cols per block.
// Fallback chain only.
// =====================================================================
template<int MG>
__global__ __launch_bounds__(256, 4)
void conv3(const float* __restrict__ in, float* __restrict__ out,
           const ushortt* __restrict__ wf,
           const float* __restrict__ cb,  const float* __restrict__ gam,
           const float* __restrict__ bet, const float* __restrict__ mn,
           const float* __restrict__ vr,  int n_pix, int lw)
{
  (void)n_pix;
  const int t = threadIdx.x;
  const int w = t>>6, lane = t&63, quad = lane>>4, l16 = lane&15;
  const int nh = w*32;
  const int row0 = blockIdx.x*(MG*16);
  const int Win = 2<<lw;
  int inb[MG];
#pragma unroll
  for (int mg=0; mg<MG; ++mg){
    const int p = row0 + mg*16 + l16;
    const int n   = p >> (2*lw);
    const int rem = p - (n << (2*lw));
    const int oy  = rem >> lw, ox = rem - (oy<<lw);
    inb[mg] = ((n*Win /*Hin==Win*/ + 2*oy)*Win + 2*ox) << 7;
  }
  f32x4 acc[MG][2];
#pragma unroll
  for (int mg=0;mg<MG;++mg){ acc[mg][0]=(f32x4){0,0,0,0}; acc[mg][1]=acc[mg][0]; }

#pragma unroll
  for (int tap=0; tap<4; ++tap){
    const int toff = (((tap>>1)*Win) + (tap&1)) << 7;
#pragma unroll
    for (int fk=0; fk<4; ++fk){
      bf16x8 ah[MG], al[MG];
#pragma unroll
      for (int mg=0; mg<MG; ++mg){
        float f[8]; load8(in + inb[mg] + toff + fk*32 + quad*8, f);
        split8(f, &ah[mg], &al[mg]);
      }
#pragma unroll
      for (int ngl=0; ngl<2; ++ngl){
        const int ng = w*2 + ngl;
        const bf16x8 bh = *(const bf16x8*)&wf[(size_t)(((tap*2+0)*4+fk)*8+ng)*512 + lane*8];
        const bf16x8 bl = *(const bf16x8*)&wf[(size_t)(((tap*2+1)*4+fk)*8+ng)*512 + lane*8];
#pragma unroll
        for (int mg=0; mg<MG; ++mg){
          acc[mg][ngl] = __builtin_amdgcn_mfma_f32_16x16x32_bf16(ah[mg], bh, acc[mg][ngl], 0,0,0);
          acc[mg][ngl] = __builtin_amdgcn_mfma_f32_16x16x32_bf16(ah[mg], bl, acc[mg][ngl], 0,0,0);
          acc[mg][ngl] = __builtin_amdgcn_mfma_f32_16x16x32_bf16(al[mg], bh, acc[mg][ngl], 0,0,0);
        }
      }
    }
  }
#pragma unroll
  for (int ngl=0; ngl<2; ++ngl){
    const int col = nh + ngl*16 + l16;
    const float sc  = gam[col]*rsqrtf(vr[col]+1e-5f);
    const float cbv = cb[col], bt = bet[col], mv = mn[col];
#pragma unroll
    for (int mg=0; mg<MG; ++mg)
#pragma unroll
      for (int r=0; r<4; ++r){
        const int pix = row0 + mg*16 + quad*4 + r;
        float v = acc[mg][ngl][r] + cbv;
        v = sc*(v - mv) + bt;
        out[(size_t)pix*D_ + col] = v>0.f ? v : 0.2f*v;
      }
  }
}

// =====================================================================
// tail stage: 16-row x 128-col conv step reading/writing LDS.
// =====================================================================
template<int WOUT>
static __device__ __forceinline__ void stage_lds(const float* __restrict__ sIn,
    float* __restrict__ sOut, float* __restrict__ gOut,
    const ushortt* __restrict__ wf,
    const float* __restrict__ cb, const float* __restrict__ gam,
    const float* __restrict__ bet, const float* __restrict__ mn,
    const float* __restrict__ vr, int t)
{
  const int w = t>>6, lane = t&63, quad = lane>>4, l16 = lane&15;
  const int nh = w*32;
  const int R  = WOUT*WOUT;
  const int Wi = 2*WOUT;
  const int p  = (l16 < R) ? l16 : 0;
  const int oy = (WOUT==4) ? (p>>2) : (WOUT==2 ? (p>>1) : 0);
  const int ox = (WOUT==4) ? (p&3)  : (WOUT==2 ? (p&1)  : 0);
  const int inb = 2*oy*Wi + 2*ox;
  f32x4 acc[2];
  acc[0]=(f32x4){0,0,0,0}; acc[1]=acc[0];
#pragma unroll
  for (int tap=0; tap<4; ++tap){
    const int toff = (tap>>1)*Wi + (tap&1);
#pragma unroll
    for (int fk=0; fk<4; ++fk){
      float f[8]; load8(sIn + (size_t)(inb+toff)*TSTR + fk*32 + quad*8, f);
      bf16x8 ah, al; split8(f, &ah, &al);
#pragma unroll
      for (int ngl=0; ngl<2; ++ngl){
        const int ng = w*2 + ngl;
        const bf16x8 bh = *(const bf16x8*)&wf[(size_t)(((tap*2+0)*4+fk)*8+ng)*512 + lane*8];
        const bf16x8 bl = *(const bf16x8*)&wf[(size_t)(((tap*2+1)*4+fk)*8+ng)*512 + lane*8];
        acc[ngl] = __builtin_amdgcn_mfma_f32_16x16x32_bf16(ah, bh, acc[ngl], 0,0,0);
        acc[ngl] = __builtin_amdgcn_mfma_f32_16x16x32_bf16(ah, bl, acc[ngl], 0,0,0);
        acc[ngl] = __builtin_amdgcn_mfma_f32_16x16x32_bf16(al, bh, acc[ngl], 0,0,0);
      }
    }
  }
#pragma unroll
  for (int ngl=0; ngl<2; ++ngl){
    const int col = nh + ngl*16 + l16;
    const float sc  = gam[col]*rsqrtf(vr[col]+1e-5f);
    const float cbv = cb[col], btv = bet[col], mv = mn[col];
#pragma unroll
    for (int r=0; r<4; ++r){
      const int row = quad*4 + r;
      if (row < R){
        float v = acc[ngl][r] + cbv;
        v = sc*(v - mv) + btv;
        v = v>0.f ? v : 0.2f*v;
        if (WOUT > 1) sOut[(size_t)row*TSTR + col] = v;
        else          gOut[col] = v;        // R==1: only row 0 stores
      }
    }
  }
}

// =====================================================================
// tail: per-(b,t) block fuses L1 -> L2 -> L3 -> L4 in LDS. 96 blocks.
// =====================================================================
__global__ __launch_bounds__(256, 2)
void tail_kernel(const float* __restrict__ bufA, const ushortt* __restrict__ wfC,
                 const float* __restrict__ cb,  const float* __restrict__ gam,
                 const float* __restrict__ bet, const float* __restrict__ mn,
                 const float* __restrict__ vr,  float* __restrict__ zbuf)
{
  __shared__ float sA[64*TSTR];  // L1 out (8x8)
  __shared__ float sB[16*TSTR];  // L2 out (4x4)
  __shared__ float sC[ 4*TSTR];  // L3 out (2x2)
  const int bt = blockIdx.x;
  const int t = threadIdx.x;
  const int w = t>>6, lane = t&63, quad = lane>>4, l16 = lane&15;
  const int nh = w*32;

  // ---- L1: bufA rows [bt*256, bt*256+256) -> sA (64 rows), MG=4/wave ----
  {
    const ushortt* wf = wfC + 131072;
    int inb[4];
#pragma unroll
    for (int mg=0; mg<4; ++mg){
      const int p = mg*16 + l16;          // local pixel in 8x8
      const int oy = p>>3, ox = p&7;
      inb[mg] = ((bt*16 + 2*oy)*16 + 2*ox) << 7;
    }
    f32x4 acc[4][2];
#pragma unroll
    for (int mg=0;mg<4;++mg){ acc[mg][0]=(f32x4){0,0,0,0}; acc[mg][1]=acc[mg][0]; }
#pragma unroll
    for (int tap=0; tap<4; ++tap){
      const int toff = (((tap>>1)*16) + (tap&1)) << 7;
#pragma unroll
      for (int fk=0; fk<4; ++fk){
        bf16x8 ah[4], al[4];
#pragma unroll
        for (int mg=0; mg<4; ++mg){
          float f[8]; load8(bufA + (size_t)inb[mg] + toff + fk*32 + quad*8, f);
          split8(f, &ah[mg], &al[mg]);
        }
#pragma unroll
        for (int ngl=0; ngl<2; ++ngl){
          const int ng = w*2 + ngl;
          const bf16x8 bh = *(const bf16x8*)&wf[(size_t)(((tap*2+0)*4+fk)*8+ng)*512 + lane*8];
          const bf16x8 bl = *(const bf16x8*)&wf[(size_t)(((tap*2+1)*4+fk)*8+ng)*512 + lane*8];
#pragma unroll
          for (int mg=0; mg<4; ++mg){
            acc[mg][ngl] = __builtin_amdgcn_mfma_f32_16x16x32_bf16(ah[mg], bh, acc[mg][ngl], 0,0,0);
            acc[mg][ngl] = __builtin_amdgcn_mfma_f32_16x16x32_bf16(ah[mg], bl, acc[mg][ngl], 0,0,0);
            acc[mg][ngl] = __builtin_amdgcn_mfma_f32_16x16x32_bf16(al[mg], bh, acc[mg][ngl], 0,0,0);
          }
        }
      }
    }
#pragma unroll
    for (int ngl=0; ngl<2; ++ngl){
      const int col = nh + ngl*16 + l16;
      const float sc  = gam[128+col]*rsqrtf(vr[128+col]+1e-5f);
      const float cbv = cb[128+col], btv = bet[128+col], mv = mn[128+col];
#pragma unroll
      for (int mg=0; mg<4; ++mg)
#pragma unroll
        for (int r=0; r<4; ++r){
          const int row = mg*16 + quad*4 + r;
          float v = acc[mg][ngl][r] + cbv;
          v = sc*(v - mv) + btv;
          sA[(size_t)row*TSTR + col] = v>0.f ? v : 0.2f*v;
        }
    }
  }
  __syncthreads();
  stage_lds<4>(sA, sB, nullptr, wfC + 262144, cb+256, gam+256, bet+256, mn+256, vr+256, t);
  __syncthreads();
  stage_lds<2>(sB, sC, nullptr, wfC + 393216, cb+384, gam+384, bet+384, mn+384, vr+384, t);
  __syncthreads();
  stage_lds<1>(sC, nullptr, zbuf + (size_t)bt*D_, wfC + 524288, cb+512, gam+512, bet+512, mn+512, vr+512, t);
}

// ---- gate: fuse dot + rFFT(1..12) + logits + top-2 softmax (1 block) ----
__global__ void gate_kernel(const float* __restrict__ z, const float* __restrict__ fw,
                            const float* __restrict__ fb, const float* __restrict__ wg,
                            float* __restrict__ gbuf)
{
  __shared__ float s[96];
  __shared__ float amp[4][12];
  __shared__ float logits[4][7];
  const int t = threadIdx.x;
  if (t < 96){
    float a = 0.f;
    for (int d=0; d<D_; d++) a = fmaf(z[t*D_+d], fw[d], a);
    s[t] = a + fb[0];
  }
  __syncthreads();
  if (t < 48){
    const int b = t / 12, kf = (t % 12) + 1;
    float re=0.f, im=0.f;
    for (int tt=0; tt<T_; tt++){
      int ph = (kf*tt) % T_;
      float ang = (float)ph * (6.283185307179586f / (float)T_);
      re = fmaf(s[b*T_+tt], cosf(ang), re);
      im = fmaf(s[b*T_+tt], sinf(ang), im);
    }
    amp[b][t%12] = sqrtf(re*re + im*im) * 0.20412414523193150f;
  }
  __syncthreads();
  if (t < 28){
    const int b = t/7, e = t - (t/7)*7;
    float a = 0.f;
    for (int k=0;k<12;k++) a = fmaf(amp[b][k], wg[k*7+e], a);
    logits[b][e] = a;
  }
  __syncthreads();
  if (t < 4){
    const int b = t;
    int i0=0; float v0=logits[b][0];
    for (int e=1;e<7;e++){ float v=logits[b][e]; if (v > v0){ v0=v; i0=e; } }
    int i1=-1; float v1=-3.4e38f;
    for (int e=0;e<7;e++){ if (e==i0) continue; float v=logits[b][e]; if (v > v1){ v1=v; i1=e; } }
    float ed = expf(v1 - v0);
    gbuf[b*4+0] = 1.f/(1.f+ed);
    gbuf[b*4+1] = ed/(1.f+ed);
    ((int*)gbuf)[b*4+2] = i0;
    ((int*)gbuf)[b*4+3] = i1;
  }
}

// =====================================================================
// expert_xb2: 32-row tiles -> acc[2][2][2] = 32 AGPR (~70 unified regs,
// 7 waves/EU) and 3072 blocks -> occupancy ceiling ~87% (vs 28-50%).
// Reads frag-ready bf16 xb. LSE epilogue (1 exp + 1 log).
// =====================================================================
__global__ __launch_bounds__(256, 6)
void expert_xb2(const ushortt* __restrict__ xb, const ushortt* __restrict__ wfe,
                const float* __restrict__ eb, const float* __restrict__ gbuf,
                float* __restrict__ outp)
{
  const int t = threadIdx.x;
  const int w = t>>6, lane = t&63, quad = lane>>4, l16 = lane&15;
  const int nh = w*32;
  const size_t row0 = (size_t)blockIdx.x * 32;
  const int b = (int)(row0 / NPB);
  const float g0 = gbuf[b*4+0], g1 = gbuf[b*4+1];
  const int e0 = ((const int*)gbuf)[b*4+2];
  const int e1 = ((const int*)gbuf)[b*4+3];
  const float lg0 = __logf(g0), lg1 = __logf(g1);

  f32x4 acc[2][2][2];   // [expert][mg][ngl]
#pragma unroll
  for (int e=0;e<2;++e)
#pragma unroll
    for (int mg=0;mg<2;++mg){ acc[e][mg][0]=(f32x4){0,0,0,0}; acc[e][mg][1]=acc[e][mg][0]; }

#pragma unroll
  for (int fk=0; fk<4; ++fk){
    bf16x8 a[2];
#pragma unroll
    for (int mg=0; mg<2; ++mg)
      a[mg] = *(const bf16x8*)&xb[(row0 + mg*16 + l16)*D_ + fk*32 + quad*8];
#pragma unroll
    for (int e=0; e<2; ++e){
      const int eg = e ? e1 : e0;
#pragma unroll
      for (int ngl=0; ngl<2; ++ngl){
        const int ng = w*2 + ngl;
        const bf16x8 bb = *(const bf16x8*)&wfe[(size_t)((eg*4+fk)*8+ng)*512 + lane*8];
#pragma unroll
        for (int mg=0; mg<2; ++mg)
          acc[e][mg][ngl] = __builtin_amdgcn_mfma_f32_16x16x32_bf16(a[mg], bb, acc[e][mg][ngl], 0,0,0);
      }
    }
  }
#pragma unroll
  for (int ngl=0; ngl<2; ++ngl){
    const int col = nh + ngl*16 + l16;
    const float be0 = eb[e0*D_ + col] + lg0;
    const float be1 = eb[e1*D_ + col] + lg1;
#pragma unroll
    for (int mg=0; mg<2; ++mg)
#pragma unroll
      for (int r=0; r<4; ++r){
        const size_t row = row0 + mg*16 + quad*4 + r;
        const float u = acc[0][mg][ngl][r] + be0;
        const float v = acc[1][mg][ngl][r] + be1;
        const float m = fmaxf(u, v);
        outp[row*D_ + col] = m + __logf(1.f + __expf(-fabsf(u - v)));
      }
  }
}

// =====================================================================
// expert (fallback path): reads fp32 x + gbuf, optional LDS staging.
// =====================================================================
template<bool WF>
__global__ __launch_bounds__(256, 3)
void expert3(const float* __restrict__ x, const float* __restrict__ ew,
             const ushortt* __restrict__ wfe, const float* __restrict__ eb,
             const float* __restrict__ gbuf, float* __restrict__ outp)
{
  __shared__ ushortt wlds[WF ? 16 : 32768];
  const int t = threadIdx.x;
  const int w = t>>6, lane = t&63, quad = lane>>4, l16 = lane&15;
  const int nh = w*32;
  const size_t row0 = (size_t)blockIdx.x * 64;
  const int b = (int)(row0 / NPB);
  const float g0 = gbuf[b*4+0], g1 = gbuf[b*4+1];
  const int e0 = ((const int*)gbuf)[b*4+2];
  const int e1 = ((const int*)gbuf)[b*4+3];

  if (!WF){
    const int el = t>>7, r7 = t&127;
    const int n0 = (r7&31)*4, k0 = (r7>>5)*16;
    const int esel = el ? e1 : e0;
#pragma unroll
    for (int h=0; h<2; ++h)
#pragma unroll
      for (int sub=0; sub<2; ++sub){
        const int kb = h*64 + k0 + sub*8;
        float4 v[8];
#pragma unroll
        for (int kk=0;kk<8;++kk)
          v[kk] = *(const float4*)&ew[(size_t)esel*16384 + (size_t)(kb+kk)*D_ + n0];
        const int fk = kb>>5, q = (kb>>3)&3;
#pragma unroll
        for (int n=0;n<4;++n){
          float f[8];
#pragma unroll
          for (int kk=0;kk<8;++kk) f[kk] = ((const float*)&v[kk])[n];
          *(bf16x8*)&wlds[(size_t)(((el*4+fk)*8 + ((n0+n)>>4))*512 + (q*16 + ((n0+n)&15))*8)] = cvt8(f);
        }
      }
    __syncthreads();
  }

  f32x4 acc[2][4][2];
#pragma unroll
  for (int e=0;e<2;++e)
#pragma unroll
    for (int mg=0;mg<4;++mg){ acc[e][mg][0]=(f32x4){0,0,0,0}; acc[e][mg][1]=acc[e][mg][0]; }

#pragma unroll
  for (int fk=0; fk<4; ++fk){
    bf16x8 a[4];
#pragma unroll
    for (int mg=0; mg<4; ++mg){
      float f[8]; load8(x + (row0 + mg*16 + l16)*D_ + fk*32 + quad*8, f);
      a[mg] = cvt8(f);
    }
#pragma unroll
    for (int e=0; e<2; ++e){
      const int eg = e ? e1 : e0;
#pragma unroll
      for (int ngl=0; ngl<2; ++ngl){
        const int ng = w*2 + ngl;
        bf16x8 bb;
        if (WF) bb = *(const bf16x8*)&wfe[(size_t)((eg*4+fk)*8+ng)*512 + lane*8];
        else    bb = *(const bf16x8*)&wlds[(size_t)((e*4+fk)*8+ng)*512 + lane*8];
#pragma unroll
        for (int mg=0; mg<4; ++mg)
          acc[e][mg][ngl] = __builtin_amdgcn_mfma_f32_16x16x32_bf16(a[mg], bb, acc[e][mg][ngl], 0,0,0);
      }
    }
  }
#pragma unroll
  for (int ngl=0; ngl<2; ++ngl){
    const int col = nh + ngl*16 + l16;
    const float be0 = eb[e0*D_ + col];
    const float be1 = eb[e1*D_ + col];
#pragma unroll
    for (int mg=0; mg<4; ++mg)
#pragma unroll
      for (int r=0; r<4; ++r){
        const size_t row = row0 + mg*16 + quad*4 + r;
        float c = g0*__expf(acc[0][mg][ngl][r] + be0) + g1*__expf(acc[1][mg][ngl][r] + be1);
        if (c == 0.f) c = 2.220446049250313e-16f;
        outp[row*D_ + col] = __logf(c);
      }
  }
}

extern "C" void kernel_launch(void* const* d_in, const int* in_sizes, int n_in,
                              void* d_out, int out_size, void* d_ws, size_t ws_size,
                              hipStream_t stream)
{
  const float* x   = (const float*)d_in[0];
  const float* cw  = (const float*)d_in[1];
  const float* cb  = (const float*)d_in[2];
  const float* gam = (const float*)d_in[3];
  const float* bet = (const float*)d_in[4];
  const float* mn  = (const float*)d_in[5];
  const float* vr  = (const float*)d_in[6];
  const float* fw  = (const float*)d_in[7];
  const float* fb  = (const float*)d_in[8];
  const float* wg  = (const float*)d_in[9];
  const float* ew  = (const float*)d_in[10];
  const float* eb  = (const float*)d_in[11];
  float* out = (float*)d_out;

  // Scratch inside d_out (50.3 MB), fully overwritten by expert at the end:
  //   wfC  [0,        1310720)   conv weight frags (hi/lo bf16)
  //   bufA [1310720,  13893632)  L0 output (24576 x 128 fp32)
  char* sb = (char*)d_out;
  ushortt* wfC = (ushortt*)sb;
  float* bufA  = (float*)(sb + 1310720);

  // Workspace (expert-phase inputs must NOT live in d_out — expert blocks
  // overwrite d_out while others still read):
  //   wfE  [0,      229376)   expert weight frags
  //   zbuf [229376, 278528)   96x128 fp32 (L4 out)
  //   gbuf [278528, 278592)   gates
  //   xb   [278592, 25444416) 98304x128 bf16 frag-ready x copy
  const size_t WFE_BYTES = (size_t)7*4*8*512*2;          // 229376
  const size_t ZB_BYTES  = (size_t)96*D_*sizeof(float);  // 49152
  const size_t XB_OFF    = WFE_BYTES + ZB_BYTES + 64;    // 278592 (16B aligned)
  const size_t XB_BYTES  = (size_t)98304*D_*2;           // 25165824
  const bool primary = ws_size >= XB_OFF + XB_BYTES;
  ushortt* wfE   = (ushortt*)d_ws;
  float* zbuf_ws = (float*)((char*)d_ws + WFE_BYTES);
  float* gbuf_ws = (float*)((char*)d_ws + WFE_BYTES + ZB_BYTES);
  ushortt* xb    = (ushortt*)((char*)d_ws + XB_OFF);

  if (primary){
    // 5 dispatches: prep -> L0(+xb, hi-occ) -> tail(L1..L4) -> gate -> expert
    prep_frags<<<96, 256, 0, stream>>>(cw, ew, wfC, wfE, 1);
    conv0_xb<<<1536, 256, 0, stream>>>(x, bufA, xb, wfC, cb, gam, bet, mn, vr);
    tail_kernel<<<96, 256, 0, stream>>>(bufA, wfC, cb, gam, bet, mn, vr, zbuf_ws);
    gate_kernel<<<1, 128, 0, stream>>>(zbuf_ws, fw, fb, wg, gbuf_ws);
    expert_xb2<<<3072, 256, 0, stream>>>(xb, wfE, eb, gbuf_ws, out);
    return;
  }

  // Fallback: verified 9-dispatch chain (221-223 us baseline)
  float* bufB  = (float*)(sb + 13893632);
  float* zbuf  = (float*)(sb + 17039360);
  float* gbuf  = (float*)d_ws;                 // 64 B
  const bool use_wf = ws_size >= (size_t)(64 + WFE_BYTES);
  ushortt* wfE2 = use_wf ? (ushortt*)((char*)d_ws + 64) : wfC;

  prep_frags<<<96, 256, 0, stream>>>(cw, ew, wfC, wfE2, use_wf ? 1 : 0);
  conv3<2><<<768, 256, 0, stream>>>(x,    bufA, wfC,          cb,     gam,     bet,     mn,     vr,     24576, 4);
  conv3<2><<<192, 256, 0, stream>>>(bufA, bufB, wfC + 131072, cb+128, gam+128, bet+128, mn+128, vr+128,  6144, 3);
  conv3<1><<< 96, 256, 0, stream>>>(bufB, bufA, wfC + 262144, cb+256, gam+256, bet+256, mn+256, vr+256,  1536, 2);
  conv3<1><<< 24, 256, 0, stream>>>(bufA, bufB, wfC + 393216, cb+384, gam+384, bet+384, mn+384, vr+384,   384, 1);
  conv3<1><<<  6, 256, 0, stream>>>(bufB, zbuf, wfC + 524288, cb+512, gam+512, bet+512, mn+512, vr+512,    96, 0);
  gate_kernel<<<1, 128, 0, stream>>>(zbuf, fw, fb, wg, gbuf);
  if (use_wf) expert3<true ><<<1536, 256, 0, stream>>>(x, ew, wfE2, eb, gbuf, out);
  else        expert3<false><<<1536, 256, 0, stream>>>(x, ew, wfE2, eb, gbuf, out);
}

// Round 7
// 221.312 us; speedup vs baseline: 1.1061x; 1.0117x over previous
//
#include <hip/hip_runtime.h>
#include <hip/hip_bf16.h>

#define D_ 128
#define T_ 24
#define NPB 24576  /* rows per batch b in expert phase: T*H*W */
#define TSTR 132   /* LDS row stride (floats) for tail stages */

typedef __attribute__((ext_vector_type(8))) short bf16x8;
typedef __attribute__((ext_vector_type(4))) float f32x4;
typedef unsigned short ushortt;

static __device__ __forceinline__ void load8(const float* p, float* dst){
  float4 a = *(const float4*)p; float4 b = *(const float4*)(p+4);
  dst[0]=a.x;dst[1]=a.y;dst[2]=a.z;dst[3]=a.w;dst[4]=b.x;dst[5]=b.y;dst[6]=b.z;dst[7]=b.w;
}
static __device__ __forceinline__ bf16x8 cvt8(const float* f){
  union { bf16x8 v; __hip_bfloat162 h[4]; } u;
#pragma unroll
  for (int i=0;i<4;i++) u.h[i] = __float22bfloat162_rn(make_float2(f[2*i], f[2*i+1]));
  return u.v;
}
static __device__ __forceinline__ void split8(const float* f, bf16x8* hh, bf16x8* ll){
  union { bf16x8 v; __hip_bfloat162 h[4]; } uh, ul;
  float lo[8];
#pragma unroll
  for (int i=0;i<4;i++){
    __hip_bfloat162 p = __float22bfloat162_rn(make_float2(f[2*i], f[2*i+1]));
    uh.h[i] = p;
    lo[2*i]   = f[2*i]   - __bfloat162float(p.x);
    lo[2*i+1] = f[2*i+1] - __bfloat162float(p.y);
  }
#pragma unroll
  for (int i=0;i<4;i++) ul.h[i] = __float22bfloat162_rn(make_float2(lo[2*i], lo[2*i+1]));
  *hh = uh.v; *ll = ul.v;
}

// =====================================================================
// prep: pack weights into MFMA-fragment-linear layout (verified R4).
// =====================================================================
__global__ void prep_frags(const float* __restrict__ cw, const float* __restrict__ ew,
                           ushortt* __restrict__ wfC, ushortt* __restrict__ wfE, int do_e)
{
  const int idx = blockIdx.x*256 + threadIdx.x;
  if (idx < 10240){
    const int l  = idx >> 11;
    const int n  = (idx >> 4) & 127;
    const int k8 = (idx & 15) * 8;
    const float* src = cw + (size_t)((l*128 + n)*128 + k8)*4;   // float4 = 4 taps
    float4 v[8];
#pragma unroll
    for (int kk=0;kk<8;++kk) v[kk] = *(const float4*)&src[kk*4];
    const int fk = k8>>5, q = (k8>>3)&3, ng = n>>4;
    const int lanoff = (q*16 + (n&15))*8;
#pragma unroll
    for (int tap=0; tap<4; ++tap){
      float f[8];
#pragma unroll
      for (int kk=0;kk<8;++kk) f[kk] = ((const float*)&v[kk])[tap];
      bf16x8 hh, ll; split8(f, &hh, &ll);
      *(bf16x8*)&wfC[(size_t)((((l*4+tap)*2+0)*4+fk)*8+ng)*512 + lanoff] = hh;
      *(bf16x8*)&wfC[(size_t)((((l*4+tap)*2+1)*4+fk)*8+ng)*512 + lanoff] = ll;
    }
  } else if (do_e && idx < 10240 + 14336){
    const int j  = idx - 10240;
    const int e  = j >> 11;
    const int n  = (j >> 4) & 127;
    const int k8 = (j & 15) * 8;
    float f[8];
#pragma unroll
    for (int kk=0;kk<8;++kk) f[kk] = ew[(size_t)(e*128 + k8+kk)*128 + n];
    const int fk = k8>>5, q = (k8>>3)&3, ng = n>>4;
    *(bf16x8*)&wfE[(size_t)((e*4+fk)*8+ng)*512 + (q*16 + (n&15))*8] = cvt8(f);
  }
}

// =====================================================================
// conv layer (global->global), MG*16 rows x 128 cols per block.
// R0-proven shape: L0 at MG=2, 768 blocks, occ4 (<41 us under drain).
// =====================================================================
template<int MG>
__global__ __launch_bounds__(256, 4)
void conv3(const float* __restrict__ in, float* __restrict__ out,
           const ushortt* __restrict__ wf,
           const float* __restrict__ cb,  const float* __restrict__ gam,
           const float* __restrict__ bet, const float* __restrict__ mn,
           const float* __restrict__ vr,  int n_pix, int lw)
{
  (void)n_pix;
  const int t = threadIdx.x;
  const int w = t>>6, lane = t&63, quad = lane>>4, l16 = lane&15;
  const int nh = w*32;
  const int row0 = blockIdx.x*(MG*16);
  const int Win = 2<<lw;
  int inb[MG];
#pragma unroll
  for (int mg=0; mg<MG; ++mg){
    const int p = row0 + mg*16 + l16;
    const int n   = p >> (2*lw);
    const int rem = p - (n << (2*lw));
    const int oy  = rem >> lw, ox = rem - (oy<<lw);
    inb[mg] = ((n*Win /*Hin==Win*/ + 2*oy)*Win + 2*ox) << 7;
  }
  f32x4 acc[MG][2];
#pragma unroll
  for (int mg=0;mg<MG;++mg){ acc[mg][0]=(f32x4){0,0,0,0}; acc[mg][1]=acc[mg][0]; }

#pragma unroll
  for (int tap=0; tap<4; ++tap){
    const int toff = (((tap>>1)*Win) + (tap&1)) << 7;
#pragma unroll
    for (int fk=0; fk<4; ++fk){
      bf16x8 ah[MG], al[MG];
#pragma unroll
      for (int mg=0; mg<MG; ++mg){
        float f[8]; load8(in + inb[mg] + toff + fk*32 + quad*8, f);
        split8(f, &ah[mg], &al[mg]);
      }
#pragma unroll
      for (int ngl=0; ngl<2; ++ngl){
        const int ng = w*2 + ngl;
        const bf16x8 bh = *(const bf16x8*)&wf[(size_t)(((tap*2+0)*4+fk)*8+ng)*512 + lane*8];
        const bf16x8 bl = *(const bf16x8*)&wf[(size_t)(((tap*2+1)*4+fk)*8+ng)*512 + lane*8];
#pragma unroll
        for (int mg=0; mg<MG; ++mg){
          acc[mg][ngl] = __builtin_amdgcn_mfma_f32_16x16x32_bf16(ah[mg], bh, acc[mg][ngl], 0,0,0);
          acc[mg][ngl] = __builtin_amdgcn_mfma_f32_16x16x32_bf16(ah[mg], bl, acc[mg][ngl], 0,0,0);
          acc[mg][ngl] = __builtin_amdgcn_mfma_f32_16x16x32_bf16(al[mg], bh, acc[mg][ngl], 0,0,0);
        }
      }
    }
  }
#pragma unroll
  for (int ngl=0; ngl<2; ++ngl){
    const int col = nh + ngl*16 + l16;
    const float sc  = gam[col]*rsqrtf(vr[col]+1e-5f);
    const float cbv = cb[col], bt = bet[col], mv = mn[col];
#pragma unroll
    for (int mg=0; mg<MG; ++mg)
#pragma unroll
      for (int r=0; r<4; ++r){
        const int pix = row0 + mg*16 + quad*4 + r;
        float v = acc[mg][ngl][r] + cbv;
        v = sc*(v - mv) + bt;
        out[(size_t)pix*D_ + col] = v>0.f ? v : 0.2f*v;
      }
  }
}

// =====================================================================
// tail stage: 16-row x 128-col conv step reading/writing LDS.
// =====================================================================
template<int WOUT>
static __device__ __forceinline__ void stage_lds(const float* __restrict__ sIn,
    float* __restrict__ sOut, float* __restrict__ gOut,
    const ushortt* __restrict__ wf,
    const float* __restrict__ cb, const float* __restrict__ gam,
    const float* __restrict__ bet, const float* __restrict__ mn,
    const float* __restrict__ vr, int t)
{
  const int w = t>>6, lane = t&63, quad = lane>>4, l16 = lane&15;
  const int nh = w*32;
  const int R  = WOUT*WOUT;
  const int Wi = 2*WOUT;
  const int p  = (l16 < R) ? l16 : 0;
  const int oy = (WOUT==4) ? (p>>2) : (WOUT==2 ? (p>>1) : 0);
  const int ox = (WOUT==4) ? (p&3)  : (WOUT==2 ? (p&1)  : 0);
  const int inb = 2*oy*Wi + 2*ox;
  f32x4 acc[2];
  acc[0]=(f32x4){0,0,0,0}; acc[1]=acc[0];
#pragma unroll
  for (int tap=0; tap<4; ++tap){
    const int toff = (tap>>1)*Wi + (tap&1);
#pragma unroll
    for (int fk=0; fk<4; ++fk){
      float f[8]; load8(sIn + (size_t)(inb+toff)*TSTR + fk*32 + quad*8, f);
      bf16x8 ah, al; split8(f, &ah, &al);
#pragma unroll
      for (int ngl=0; ngl<2; ++ngl){
        const int ng = w*2 + ngl;
        const bf16x8 bh = *(const bf16x8*)&wf[(size_t)(((tap*2+0)*4+fk)*8+ng)*512 + lane*8];
        const bf16x8 bl = *(const bf16x8*)&wf[(size_t)(((tap*2+1)*4+fk)*8+ng)*512 + lane*8];
        acc[ngl] = __builtin_amdgcn_mfma_f32_16x16x32_bf16(ah, bh, acc[ngl], 0,0,0);
        acc[ngl] = __builtin_amdgcn_mfma_f32_16x16x32_bf16(ah, bl, acc[ngl], 0,0,0);
        acc[ngl] = __builtin_amdgcn_mfma_f32_16x16x32_bf16(al, bh, acc[ngl], 0,0,0);
      }
    }
  }
#pragma unroll
  for (int ngl=0; ngl<2; ++ngl){
    const int col = nh + ngl*16 + l16;
    const float sc  = gam[col]*rsqrtf(vr[col]+1e-5f);
    const float cbv = cb[col], btv = bet[col], mv = mn[col];
#pragma unroll
    for (int r=0; r<4; ++r){
      const int row = quad*4 + r;
      if (row < R){
        float v = acc[ngl][r] + cbv;
        v = sc*(v - mv) + btv;
        v = v>0.f ? v : 0.2f*v;
        if (WOUT > 1) sOut[(size_t)row*TSTR + col] = v;
        else          gOut[col] = v;        // R==1: only row 0 stores
      }
    }
  }
}

// =====================================================================
// tail: per-(b,t) block fuses L1 -> L2 -> L3 -> L4 in LDS. 96 blocks.
// =====================================================================
__global__ __launch_bounds__(256, 2)
void tail_kernel(const float* __restrict__ bufA, const ushortt* __restrict__ wfC,
                 const float* __restrict__ cb,  const float* __restrict__ gam,
                 const float* __restrict__ bet, const float* __restrict__ mn,
                 const float* __restrict__ vr,  float* __restrict__ zbuf)
{
  __shared__ float sA[64*TSTR];  // L1 out (8x8)
  __shared__ float sB[16*TSTR];  // L2 out (4x4)
  __shared__ float sC[ 4*TSTR];  // L3 out (2x2)
  const int bt = blockIdx.x;
  const int t = threadIdx.x;
  const int w = t>>6, lane = t&63, quad = lane>>4, l16 = lane&15;
  const int nh = w*32;

  // ---- L1: bufA rows [bt*256, bt*256+256) -> sA (64 rows), MG=4/wave ----
  {
    const ushortt* wf = wfC + 131072;
    int inb[4];
#pragma unroll
    for (int mg=0; mg<4; ++mg){
      const int p = mg*16 + l16;          // local pixel in 8x8
      const int oy = p>>3, ox = p&7;
      inb[mg] = ((bt*16 + 2*oy)*16 + 2*ox) << 7;
    }
    f32x4 acc[4][2];
#pragma unroll
    for (int mg=0;mg<4;++mg){ acc[mg][0]=(f32x4){0,0,0,0}; acc[mg][1]=acc[mg][0]; }
#pragma unroll
    for (int tap=0; tap<4; ++tap){
      const int toff = (((tap>>1)*16) + (tap&1)) << 7;
#pragma unroll
      for (int fk=0; fk<4; ++fk){
        bf16x8 ah[4], al[4];
#pragma unroll
        for (int mg=0; mg<4; ++mg){
          float f[8]; load8(bufA + (size_t)inb[mg] + toff + fk*32 + quad*8, f);
          split8(f, &ah[mg], &al[mg]);
        }
#pragma unroll
        for (int ngl=0; ngl<2; ++ngl){
          const int ng = w*2 + ngl;
          const bf16x8 bh = *(const bf16x8*)&wf[(size_t)(((tap*2+0)*4+fk)*8+ng)*512 + lane*8];
          const bf16x8 bl = *(const bf16x8*)&wf[(size_t)(((tap*2+1)*4+fk)*8+ng)*512 + lane*8];
#pragma unroll
          for (int mg=0; mg<4; ++mg){
            acc[mg][ngl] = __builtin_amdgcn_mfma_f32_16x16x32_bf16(ah[mg], bh, acc[mg][ngl], 0,0,0);
            acc[mg][ngl] = __builtin_amdgcn_mfma_f32_16x16x32_bf16(ah[mg], bl, acc[mg][ngl], 0,0,0);
            acc[mg][ngl] = __builtin_amdgcn_mfma_f32_16x16x32_bf16(al[mg], bh, acc[mg][ngl], 0,0,0);
          }
        }
      }
    }
#pragma unroll
    for (int ngl=0; ngl<2; ++ngl){
      const int col = nh + ngl*16 + l16;
      const float sc  = gam[128+col]*rsqrtf(vr[128+col]+1e-5f);
      const float cbv = cb[128+col], btv = bet[128+col], mv = mn[128+col];
#pragma unroll
      for (int mg=0; mg<4; ++mg)
#pragma unroll
        for (int r=0; r<4; ++r){
          const int row = mg*16 + quad*4 + r;
          float v = acc[mg][ngl][r] + cbv;
          v = sc*(v - mv) + btv;
          sA[(size_t)row*TSTR + col] = v>0.f ? v : 0.2f*v;
        }
    }
  }
  __syncthreads();
  stage_lds<4>(sA, sB, nullptr, wfC + 262144, cb+256, gam+256, bet+256, mn+256, vr+256, t);
  __syncthreads();
  stage_lds<2>(sB, sC, nullptr, wfC + 393216, cb+384, gam+384, bet+384, mn+384, vr+384, t);
  __syncthreads();
  stage_lds<1>(sC, nullptr, zbuf + (size_t)bt*D_, wfC + 524288, cb+512, gam+512, bet+512, mn+512, vr+512, t);
}

// ---- gate: fuse dot + rFFT(1..12) + logits + top-2 softmax (1 block) ----
__global__ void gate_kernel(const float* __restrict__ z, const float* __restrict__ fw,
                            const float* __restrict__ fb, const float* __restrict__ wg,
                            float* __restrict__ gbuf)
{
  __shared__ float s[96];
  __shared__ float amp[4][12];
  __shared__ float logits[4][7];
  const int t = threadIdx.x;
  if (t < 96){
    float a = 0.f;
    for (int d=0; d<D_; d++) a = fmaf(z[t*D_+d], fw[d], a);
    s[t] = a + fb[0];
  }
  __syncthreads();
  if (t < 48){
    const int b = t / 12, kf = (t % 12) + 1;
    float re=0.f, im=0.f;
    for (int tt=0; tt<T_; tt++){
      int ph = (kf*tt) % T_;
      float ang = (float)ph * (6.283185307179586f / (float)T_);
      re = fmaf(s[b*T_+tt], cosf(ang), re);
      im = fmaf(s[b*T_+tt], sinf(ang), im);
    }
    amp[b][t%12] = sqrtf(re*re + im*im) * 0.20412414523193150f;
  }
  __syncthreads();
  if (t < 28){
    const int b = t/7, e = t - (t/7)*7;
    float a = 0.f;
    for (int k=0;k<12;k++) a = fmaf(amp[b][k], wg[k*7+e], a);
    logits[b][e] = a;
  }
  __syncthreads();
  if (t < 4){
    const int b = t;
    int i0=0; float v0=logits[b][0];
    for (int e=1;e<7;e++){ float v=logits[b][e]; if (v > v0){ v0=v; i0=e; } }
    int i1=-1; float v1=-3.4e38f;
    for (int e=0;e<7;e++){ if (e==i0) continue; float v=logits[b][e]; if (v > v1){ v1=v; i1=e; } }
    float ed = expf(v1 - v0);
    gbuf[b*4+0] = 1.f/(1.f+ed);
    gbuf[b*4+1] = ed/(1.f+ed);
    ((int*)gbuf)[b*4+2] = i0;
    ((int*)gbuf)[b*4+3] = i1;
  }
}

// =====================================================================
// expert_x32: reads fp32 x directly (L3-assisted: R2/R6 FETCH shows ~half
// of x comes from cache). 32-row tiles, 3072 blocks, occ6 (R6's proven
// occupancy win), LSE epilogue (1 exp + 1 log; R4-verified numerics).
// =====================================================================
__global__ __launch_bounds__(256, 6)
void expert_x32(const float* __restrict__ x, const ushortt* __restrict__ wfe,
                const float* __restrict__ eb, const float* __restrict__ gbuf,
                float* __restrict__ outp)
{
  const int t = threadIdx.x;
  const int w = t>>6, lane = t&63, quad = lane>>4, l16 = lane&15;
  const int nh = w*32;
  const size_t row0 = (size_t)blockIdx.x * 32;
  const int b = (int)(row0 / NPB);
  const float g0 = gbuf[b*4+0], g1 = gbuf[b*4+1];
  const int e0 = ((const int*)gbuf)[b*4+2];
  const int e1 = ((const int*)gbuf)[b*4+3];
  const float lg0 = __logf(g0), lg1 = __logf(g1);

  f32x4 acc[2][2][2];   // [expert][mg][ngl]
#pragma unroll
  for (int e=0;e<2;++e)
#pragma unroll
    for (int mg=0;mg<2;++mg){ acc[e][mg][0]=(f32x4){0,0,0,0}; acc[e][mg][1]=acc[e][mg][0]; }

#pragma unroll
  for (int fk=0; fk<4; ++fk){
    bf16x8 a[2];
#pragma unroll
    for (int mg=0; mg<2; ++mg){
      float f[8]; load8(x + (row0 + mg*16 + l16)*D_ + fk*32 + quad*8, f);
      a[mg] = cvt8(f);
    }
#pragma unroll
    for (int e=0; e<2; ++e){
      const int eg = e ? e1 : e0;
#pragma unroll
      for (int ngl=0; ngl<2; ++ngl){
        const int ng = w*2 + ngl;
        const bf16x8 bb = *(const bf16x8*)&wfe[(size_t)((eg*4+fk)*8+ng)*512 + lane*8];
#pragma unroll
        for (int mg=0; mg<2; ++mg)
          acc[e][mg][ngl] = __builtin_amdgcn_mfma_f32_16x16x32_bf16(a[mg], bb, acc[e][mg][ngl], 0,0,0);
      }
    }
  }
#pragma unroll
  for (int ngl=0; ngl<2; ++ngl){
    const int col = nh + ngl*16 + l16;
    const float be0 = eb[e0*D_ + col] + lg0;
    const float be1 = eb[e1*D_ + col] + lg1;
#pragma unroll
    for (int mg=0; mg<2; ++mg)
#pragma unroll
      for (int r=0; r<4; ++r){
        const size_t row = row0 + mg*16 + quad*4 + r;
        const float u = acc[0][mg][ngl][r] + be0;
        const float v = acc[1][mg][ngl][r] + be1;
        const float m = fmaxf(u, v);
        outp[row*D_ + col] = m + __logf(1.f + __expf(-fabsf(u - v)));
      }
  }
}

// =====================================================================
// expert (fallback path): reads fp32 x + gbuf, optional LDS staging.
// =====================================================================
template<bool WF>
__global__ __launch_bounds__(256, 3)
void expert3(const float* __restrict__ x, const float* __restrict__ ew,
             const ushortt* __restrict__ wfe, const float* __restrict__ eb,
             const float* __restrict__ gbuf, float* __restrict__ outp)
{
  __shared__ ushortt wlds[WF ? 16 : 32768];
  const int t = threadIdx.x;
  const int w = t>>6, lane = t&63, quad = lane>>4, l16 = lane&15;
  const int nh = w*32;
  const size_t row0 = (size_t)blockIdx.x * 64;
  const int b = (int)(row0 / NPB);
  const float g0 = gbuf[b*4+0], g1 = gbuf[b*4+1];
  const int e0 = ((const int*)gbuf)[b*4+2];
  const int e1 = ((const int*)gbuf)[b*4+3];

  if (!WF){
    const int el = t>>7, r7 = t&127;
    const int n0 = (r7&31)*4, k0 = (r7>>5)*16;
    const int esel = el ? e1 : e0;
#pragma unroll
    for (int h=0; h<2; ++h)
#pragma unroll
      for (int sub=0; sub<2; ++sub){
        const int kb = h*64 + k0 + sub*8;
        float4 v[8];
#pragma unroll
        for (int kk=0;kk<8;++kk)
          v[kk] = *(const float4*)&ew[(size_t)esel*16384 + (size_t)(kb+kk)*D_ + n0];
        const int fk = kb>>5, q = (kb>>3)&3;
#pragma unroll
        for (int n=0;n<4;++n){
          float f[8];
#pragma unroll
          for (int kk=0;kk<8;++kk) f[kk] = ((const float*)&v[kk])[n];
          *(bf16x8*)&wlds[(size_t)(((el*4+fk)*8 + ((n0+n)>>4))*512 + (q*16 + ((n0+n)&15))*8)] = cvt8(f);
        }
      }
    __syncthreads();
  }

  f32x4 acc[2][4][2];
#pragma unroll
  for (int e=0;e<2;++e)
#pragma unroll
    for (int mg=0;mg<4;++mg){ acc[e][mg][0]=(f32x4){0,0,0,0}; acc[e][mg][1]=acc[e][mg][0]; }

#pragma unroll
  for (int fk=0; fk<4; ++fk){
    bf16x8 a[4];
#pragma unroll
    for (int mg=0; mg<4; ++mg){
      float f[8]; load8(x + (row0 + mg*16 + l16)*D_ + fk*32 + quad*8, f);
      a[mg] = cvt8(f);
    }
#pragma unroll
    for (int e=0; e<2; ++e){
      const int eg = e ? e1 : e0;
#pragma unroll
      for (int ngl=0; ngl<2; ++ngl){
        const int ng = w*2 + ngl;
        bf16x8 bb;
        if (WF) bb = *(const bf16x8*)&wfe[(size_t)((eg*4+fk)*8+ng)*512 + lane*8];
        else    bb = *(const bf16x8*)&wlds[(size_t)((e*4+fk)*8+ng)*512 + lane*8];
#pragma unroll
        for (int mg=0; mg<4; ++mg)
          acc[e][mg][ngl] = __builtin_amdgcn_mfma_f32_16x16x32_bf16(a[mg], bb, acc[e][mg][ngl], 0,0,0);
      }
    }
  }
#pragma unroll
  for (int ngl=0; ngl<2; ++ngl){
    const int col = nh + ngl*16 + l16;
    const float be0 = eb[e0*D_ + col];
    const float be1 = eb[e1*D_ + col];
#pragma unroll
    for (int mg=0; mg<4; ++mg)
#pragma unroll
      for (int r=0; r<4; ++r){
        const size_t row = row0 + mg*16 + quad*4 + r;
        float c = g0*__expf(acc[0][mg][ngl][r] + be0) + g1*__expf(acc[1][mg][ngl][r] + be1);
        if (c == 0.f) c = 2.220446049250313e-16f;
        outp[row*D_ + col] = __logf(c);
      }
  }
}

extern "C" void kernel_launch(void* const* d_in, const int* in_sizes, int n_in,
                              void* d_out, int out_size, void* d_ws, size_t ws_size,
                              hipStream_t stream)
{
  const float* x   = (const float*)d_in[0];
  const float* cw  = (const float*)d_in[1];
  const float* cb  = (const float*)d_in[2];
  const float* gam = (const float*)d_in[3];
  const float* bet = (const float*)d_in[4];
  const float* mn  = (const float*)d_in[5];
  const float* vr  = (const float*)d_in[6];
  const float* fw  = (const float*)d_in[7];
  const float* fb  = (const float*)d_in[8];
  const float* wg  = (const float*)d_in[9];
  const float* ew  = (const float*)d_in[10];
  const float* eb  = (const float*)d_in[11];
  float* out = (float*)d_out;

  // Scratch inside d_out (50.3 MB), fully overwritten by expert at the end:
  //   wfC  [0,        1310720)   conv weight frags (hi/lo bf16)
  //   bufA [1310720,  13893632)  L0 output (24576 x 128 fp32)
  char* sb = (char*)d_out;
  ushortt* wfC = (ushortt*)sb;
  float* bufA  = (float*)(sb + 1310720);

  // Workspace (expert-phase inputs must NOT live in d_out — expert blocks
  // overwrite d_out while others still read):
  //   wfE  [0,      229376)   expert weight frags
  //   zbuf [229376, 278528)   96x128 fp32 (L4 out)
  //   gbuf [278528, 278592)   gates
  const size_t WFE_BYTES = (size_t)7*4*8*512*2;          // 229376
  const size_t ZB_BYTES  = (size_t)96*D_*sizeof(float);  // 49152
  const bool primary = ws_size >= WFE_BYTES + ZB_BYTES + 64;
  ushortt* wfE   = (ushortt*)d_ws;
  float* zbuf_ws = (float*)((char*)d_ws + WFE_BYTES);
  float* gbuf_ws = (float*)((char*)d_ws + WFE_BYTES + ZB_BYTES);

  if (primary){
    // 5 dispatches: prep -> L0 -> tail(L1..L4) -> gate -> expert
    prep_frags<<<96, 256, 0, stream>>>(cw, ew, wfC, wfE, 1);
    conv3<2><<<768, 256, 0, stream>>>(x, bufA, wfC, cb, gam, bet, mn, vr, 24576, 4);
    tail_kernel<<<96, 256, 0, stream>>>(bufA, wfC, cb, gam, bet, mn, vr, zbuf_ws);
    gate_kernel<<<1, 128, 0, stream>>>(zbuf_ws, fw, fb, wg, gbuf_ws);
    expert_x32<<<3072, 256, 0, stream>>>(x, wfE, eb, gbuf_ws, out);
    return;
  }

  // Fallback: verified 9-dispatch chain (221-223 us baseline)
  float* bufB  = (float*)(sb + 13893632);
  float* zbuf  = (float*)(sb + 17039360);
  float* gbuf  = (float*)d_ws;                 // 64 B
  const bool use_wf = ws_size >= (size_t)(64 + WFE_BYTES);
  ushortt* wfE2 = use_wf ? (ushortt*)((char*)d_ws + 64) : wfC;

  prep_frags<<<96, 256, 0, stream>>>(cw, ew, wfC, wfE2, use_wf ? 1 : 0);
  conv3<2><<<768, 256, 0, stream>>>(x,    bufA, wfC,          cb,     gam,     bet,     mn,     vr,     24576, 4);
  conv3<2><<<192, 256, 0, stream>>>(bufA, bufB, wfC + 131072, cb+128, gam+128, bet+128, mn+128, vr+128,  6144, 3);
  conv3<1><<< 96, 256, 0, stream>>>(bufB, bufA, wfC + 262144, cb+256, gam+256, bet+256, mn+256, vr+256,  1536, 2);
  conv3<1><<< 24, 256, 0, stream>>>(bufA, bufB, wfC + 393216, cb+384, gam+384, bet+384, mn+384, vr+384,   384, 1);
  conv3<1><<<  6, 256, 0, stream>>>(bufB, zbuf, wfC + 524288, cb+512, gam+512, bet+512, mn+512, vr+512,    96, 0);
  gate_kernel<<<1, 128, 0, stream>>>(zbuf, fw, fb, wg, gbuf);
  if (use_wf) expert3<true ><<<1536, 256, 0, stream>>>(x, ew, wfE2, eb, gbuf, out);
  else        expert3<false><<<1536, 256, 0, stream>>>(x, ew, wfE2, eb, gbuf, out);
}